// Round 16
// baseline (252.340 us; speedup 1.0000x reference)
//
#include <hip/hip_runtime.h>
#include <hip/hip_bf16.h>

#define N_NODES 50000
#define N_REL   16
#define DIM     128
#define NBLK    4
#define BS      32
#define N_EDGES 800000
#define NSEG    (N_NODES * N_REL)
#define SCAN_BLK 1024
#define N_SCAN_BLKS ((NSEG + SCAN_BLK - 1) / SCAN_BLK)
#define NWT     (N_NODES / 16)        // 3125 wave-tiles of 16 nodes
#define NWTB    ((NWT + 3) / 4)       // 782 fused blocks per y-slice
#define SCATB   ((N_EDGES + 511) / 512)  // 1563 scatter blocks (2 edges/thread)

typedef __attribute__((ext_vector_type(8))) short s8v;            // 8 bf16
typedef __attribute__((ext_vector_type(8))) unsigned short u8v;   // 8 bf16 bits
typedef __attribute__((ext_vector_type(4))) float f4v;            // mfma C/D

__device__ __forceinline__ float bf2f(unsigned short u) {
    return __uint_as_float(((unsigned int)u) << 16);
}
__device__ __forceinline__ unsigned short f2bfbits(float f) {   // RNE
    unsigned int u = __float_as_uint(f);
    return (unsigned short)((u + 0x7fffu + ((u >> 16) & 1u)) >> 16);
}

// ---------------------------------------------------------------------------
// Prep (+zero cnt/used): convert W/root to bf16 A-fragment lane order and
// grid-stride zero the 6.4MB cnt+used region.
// ---------------------------------------------------------------------------
__global__ __launch_bounds__(256) void prep_kernel(const float* __restrict__ W1,
                                                   const float* __restrict__ W2,
                                                   const float* __restrict__ r1,
                                                   const float* __restrict__ r2,
                                                   ushort* __restrict__ WB1,
                                                   ushort* __restrict__ WB2,
                                                   ushort* __restrict__ RB1,
                                                   ushort* __restrict__ RB2,
                                                   uint4* __restrict__ zero_base) {
    int t = blockIdx.x * 256 + threadIdx.x;
    for (int i = t; i < (2 * NSEG) / 4; i += 1152 * 256)
        zero_base[i] = make_uint4(0u, 0u, 0u, 0u);

    if (t < 262144) {                               // WB1 / WB2
        const float* W = (t < 131072) ? W1 : W2;
        ushort* WB     = (t < 131072) ? WB1 : WB2;
        int idx = t & 131071;
        int i  = idx & 7;
        int lm = (idx >> 3) & 15;
        int kg = (idx >> 7) & 3;
        int mt = (idx >> 9) & 1;
        int b  = (idx >> 10) & 3;
        int r  = idx >> 12;
        WB[idx] = f2bfbits(W[((size_t)(r * 4 + b) * 32 + kg * 8 + i) * 32 + mt * 16 + lm]);
    } else if (t < 294912) {                        // RB1 / RB2
        int u = t - 262144;
        const float* R = (u < 16384) ? r1 : r2;
        ushort* RB     = (u < 16384) ? RB1 : RB2;
        int idx = u & 16383;
        int i  = idx & 7;
        int lm = (idx >> 3) & 15;
        int kg = (idx >> 7) & 3;
        int kc = (idx >> 9) & 3;
        int mt = (idx >> 11) & 7;
        RB[idx] = f2bfbits(R[(size_t)(kc * 32 + kg * 8 + i) * DIM + mt * 16 + lm]);
    }
}

// ---------------------------------------------------------------------------
// CSR build: count (+used flag) -> joint scan {cnt,used} -> segd {cursor,cnt}
// (bsum applied by consumers); scatter merged into fused1, INTERLEAVED.
// ---------------------------------------------------------------------------
__global__ __launch_bounds__(256) void count_kernel(const int* __restrict__ src,
                                                    const int* __restrict__ dst,
                                                    const int* __restrict__ et,
                                                    int* __restrict__ cnt,
                                                    int* __restrict__ used, int E) {
    int e = blockIdx.x * 256 + threadIdx.x;
    if (e < E) {
        int r = et[e];
        atomicAdd(&cnt[dst[e] * N_REL + r], 1);
        used[r * N_NODES + src[e]] = 1;        // benign race, all write 1
    }
}

// joint scan: segd[idx] = {block-local excl prefix of cnt, cnt[idx]},
// cmap[idx] = block-local excl prefix of used.
__global__ __launch_bounds__(256) void scan1j_kernel(const int* __restrict__ cnt,
                                                     const int* __restrict__ used,
                                                     int2* __restrict__ segd,
                                                     int* __restrict__ cmap,
                                                     int2* __restrict__ bsum, int M) {
    const int t = threadIdx.x;
    const int base = blockIdx.x * SCAN_BLK + t * 4;
    int c[4], u[4];
#pragma unroll
    for (int i = 0; i < 4; ++i) {
        int idx = base + i;
        c[i] = (idx < M) ? cnt[idx] : 0;
        u[i] = (idx < M) ? used[idx] : 0;
    }
    int cs = c[0] + c[1] + c[2] + c[3];
    int us = u[0] + u[1] + u[2] + u[3];
    const int lane = t & 63, wid = t >> 6;
    int cinc = cs, uinc = us;
    for (int d = 1; d < 64; d <<= 1) {
        int a = __shfl_up(cinc, d, 64);
        int b = __shfl_up(uinc, d, 64);
        if (lane >= d) { cinc += a; uinc += b; }
    }
    __shared__ int cw[5], uw[5];
    if (lane == 63) { cw[wid] = cinc; uw[wid] = uinc; }
    __syncthreads();
    if (t == 0) {
        int a = 0, b = 0;
        for (int w = 0; w < 4; ++w) {
            int x = cw[w]; cw[w] = a; a += x;
            int y = uw[w]; uw[w] = b; b += y;
        }
        cw[4] = a; uw[4] = b;
    }
    __syncthreads();
    int cex = cinc - cs + cw[wid];
    int uex = uinc - us + uw[wid];
#pragma unroll
    for (int i = 0; i < 4; ++i) {
        int idx = base + i;
        if (idx < M) { segd[idx] = make_int2(cex, c[i]); cmap[idx] = uex; }
        cex += c[i]; uex += u[i];
    }
    if (t == 0) bsum[blockIdx.x] = make_int2(cw[4], uw[4]);
}

__global__ __launch_bounds__(1024) void scan2j_kernel(int2* __restrict__ bsum, int nb) {
    const int t = threadIdx.x;
    int2 s = (t < nb) ? bsum[t] : make_int2(0, 0);
    const int lane = t & 63, wid = t >> 6;
    int ci = s.x, ui = s.y;
    for (int d = 1; d < 64; d <<= 1) {
        int a = __shfl_up(ci, d, 64);
        int b = __shfl_up(ui, d, 64);
        if (lane >= d) { ci += a; ui += b; }
    }
    __shared__ int cw[16], uw[16];
    if (lane == 63) { cw[wid] = ci; uw[wid] = ui; }
    __syncthreads();
    if (t == 0) {
        int a = 0, b = 0;
        for (int w = 0; w < 16; ++w) {
            int x = cw[w]; cw[w] = a; a += x;
            int y = uw[w]; uw[w] = b; b += y;
        }
    }
    __syncthreads();
    if (t < nb) bsum[t] = make_int2(ci - s.x + cw[wid], ui - s.y + uw[wid]);
}

// slow-fallback scan (single array) + scatter (srcs list)
__global__ __launch_bounds__(256) void scan1_kernel(const int* __restrict__ in,
                                                    int* __restrict__ out,
                                                    int* __restrict__ bsum, int M) {
    const int t = threadIdx.x;
    const int base = blockIdx.x * SCAN_BLK + t * 4;
    int v0 = (base + 0 < M) ? in[base + 0] : 0;
    int v1 = (base + 1 < M) ? in[base + 1] : 0;
    int v2 = (base + 2 < M) ? in[base + 2] : 0;
    int v3 = (base + 3 < M) ? in[base + 3] : 0;
    const int s = v0 + v1 + v2 + v3;
    const int lane = t & 63, wid = t >> 6;
    int inc = s;
    for (int d = 1; d < 64; d <<= 1) {
        int u = __shfl_up(inc, d, 64);
        if (lane >= d) inc += u;
    }
    __shared__ int wsum[5];
    if (lane == 63) wsum[wid] = inc;
    __syncthreads();
    if (t == 0) {
        int a = 0;
        for (int w = 0; w < 4; ++w) { int u = wsum[w]; wsum[w] = a; a += u; }
        wsum[4] = a;
    }
    __syncthreads();
    const int ex = inc - s + wsum[wid];
    if (base + 0 < M) out[base + 0] = ex;
    if (base + 1 < M) out[base + 1] = ex + v0;
    if (base + 2 < M) out[base + 2] = ex + v0 + v1;
    if (base + 3 < M) out[base + 3] = ex + v0 + v1 + v2;
    if (t == 0) bsum[blockIdx.x] = wsum[4];
}

__global__ __launch_bounds__(1024) void scan2_kernel(int* __restrict__ bsum, int nb) {
    const int t = threadIdx.x;
    int s = (t < nb) ? bsum[t] : 0;
    const int lane = t & 63, wid = t >> 6;
    int inc = s;
    for (int d = 1; d < 64; d <<= 1) {
        int u = __shfl_up(inc, d, 64);
        if (lane >= d) inc += u;
    }
    __shared__ int wsum[16];
    if (lane == 63) wsum[wid] = inc;
    __syncthreads();
    if (t == 0) {
        int a = 0;
        for (int w = 0; w < 16; ++w) { int u = wsum[w]; wsum[w] = a; a += u; }
    }
    __syncthreads();
    const int ex = inc - s + wsum[wid];
    if (t < nb) bsum[t] = ex;
}

__global__ __launch_bounds__(256) void scan3_kernel(int* __restrict__ out,
                                                    const int* __restrict__ bsum, int M) {
    int i = blockIdx.x * 256 + threadIdx.x;
    if (i < M) out[i] += bsum[i / SCAN_BLK];
}

__global__ __launch_bounds__(256) void scatter_old_kernel(const int* __restrict__ src,
                                                          const int* __restrict__ dst,
                                                          const int* __restrict__ et,
                                                          int* __restrict__ off,
                                                          int* __restrict__ srcs, int E) {
    int e = blockIdx.x * 256 + threadIdx.x;
    if (e < E) {
        int seg = dst[e] * N_REL + et[e];
        int pos = atomicAdd(&off[seg], 1);
        srcs[pos] = src[e];
    }
}

// ---------------------------------------------------------------------------
// FUSED transform (+merged scatter, INTERLEAVED: odd blocks = scatter, even
// blocks = fused). Fused part: relation-split (8 rels per y-slice), tree
// rowmax, magic-rounding int8 quantize, compact table; dense root GEMM
// split across y (mt 0-3 / 4-7).
// ---------------------------------------------------------------------------
template<bool IN_BF16, bool OUT_BF16, bool RELU, bool WITH_SCATTER>
__global__ __launch_bounds__(256) void fused_kernel(const void* __restrict__ xin,
                                                    const ushort* __restrict__ WB,
                                                    const ushort* __restrict__ RB,
                                                    const float* __restrict__ bias,
                                                    const int* __restrict__ used,
                                                    const int* __restrict__ cmap,
                                                    const int2* __restrict__ bsum,
                                                    char* __restrict__ tab,
                                                    float* __restrict__ scl,
                                                    void* __restrict__ outv,
                                                    const int* __restrict__ src,
                                                    const int* __restrict__ dstv,
                                                    const int* __restrict__ et,
                                                    int2* __restrict__ segd,
                                                    int2* __restrict__ evec) {
    int fid;
    if (WITH_SCATTER) {
        const int bid = blockIdx.x;
        if (bid & 1) {
            // ---- scatter (odd blocks): 2 edges/thread; cursor+cnt share line ----
            const int e0 = (bid >> 1) * 512 + threadIdx.x;
#pragma unroll
            for (int q = 0; q < 2; ++q) {
                const int e = e0 + q * 256;
                if (e < N_EDGES) {
                    int r = et[e];
                    int seg = dstv[e] * N_REL + r;
                    int pos = atomicAdd(&segd[seg].x, 1) + bsum[seg >> 10].x;
                    float inv = 1.0f / (float)segd[seg].y;
                    int grow = r * N_NODES + src[e];
                    int g = cmap[grow] + bsum[grow >> 10].y;
                    evec[pos] = make_int2(g, __float_as_int(inv));
                }
            }
            return;
        }
        fid = bid >> 1;          // even blocks: 0..2*NWTB-1
    } else {
        fid = blockIdx.x;
    }

    const int ybit = (fid >= NWTB) ? 1 : 0;
    const int xb   = fid - ybit * NWTB;
    const int wv = threadIdx.x >> 6;
    const int l  = threadIdx.x & 63;
    const int wt = xb * 4 + wv;
    if (wt >= NWT) return;
    const int rbase = ybit * 8;
    const int lm = l & 15;
    const int kg = l >> 4;
    const int node = wt * 16 + lm;

    // x row fragments for all 4 K-blocks (shared by both parts)
    s8v bfr[4];
#pragma unroll
    for (int b = 0; b < 4; ++b) {
        if (IN_BF16) {
            const ushort* xp = (const ushort*)xin + (size_t)node * DIM + b * BS + kg * 8;
            u8v u = *(const u8v*)xp;
#pragma unroll
            for (int i = 0; i < 8; ++i) {
                unsigned short us = u[i];
                if (RELU) us = (us & 0x8000u) ? (unsigned short)0 : us;
                bfr[b][i] = (short)us;
            }
        } else {
            const float* xp = (const float*)xin + (size_t)node * DIM + b * BS + kg * 8;
#pragma unroll
            for (int i = 0; i < 8; ++i) {
                float v = xp[i];
                if (RELU) v = fmaxf(v, 0.f);
                bfr[b][i] = (short)f2bfbits(v);
            }
        }
    }

    // ---- part 1: int8 message table, 8 relations for this y ----
    const float MAGIC = 12582912.0f;   // 1.5 * 2^23: low byte = int8(RNE(x))
#pragma unroll 2
    for (int ri = 0; ri < 8; ++ri) {
        const int rr = rbase + ri;
        const int grow = rr * N_NODES + node;
        const int flag = used[grow];            // hoisted loads
        const int cid  = cmap[grow] + bsum[grow >> 10].y;
        f4v acc[4][2];
#pragma unroll
        for (int b = 0; b < 4; ++b) {
#pragma unroll
            for (int mt = 0; mt < 2; ++mt) {
                s8v afrag = *(const s8v*)&WB[((((rr * 4 + b) * 2 + mt) * 4 + kg) * 16 + lm) * 8];
                f4v z = {0.f, 0.f, 0.f, 0.f};
                acc[b][mt] = __builtin_amdgcn_mfma_f32_16x16x32_bf16(afrag, bfr[b], z, 0, 0, 0);
            }
        }
        // rowmax: depth-5 tree over 32 in-lane values, then 2 shfl_xor
        float t8[8];
#pragma unroll
        for (int b = 0; b < 4; ++b)
#pragma unroll
            for (int mt = 0; mt < 2; ++mt)
                t8[b * 2 + mt] = fmaxf(fmaxf(fabsf(acc[b][mt][0]), fabsf(acc[b][mt][1])),
                                       fmaxf(fabsf(acc[b][mt][2]), fabsf(acc[b][mt][3])));
        float m = fmaxf(fmaxf(fmaxf(t8[0], t8[1]), fmaxf(t8[2], t8[3])),
                        fmaxf(fmaxf(t8[4], t8[5]), fmaxf(t8[6], t8[7])));
        m = fmaxf(m, __shfl_xor(m, 16, 64));
        m = fmaxf(m, __shfl_xor(m, 32, 64));
        m = fmaxf(m, 1e-30f);

        if (flag) {
            const float qs = 127.0f / m;
            unsigned int d[8];
#pragma unroll
            for (int b = 0; b < 4; ++b) {
#pragma unroll
                for (int mt = 0; mt < 2; ++mt) {
                    unsigned f0 = __float_as_uint(fmaf(acc[b][mt][0], qs, MAGIC));
                    unsigned f1 = __float_as_uint(fmaf(acc[b][mt][1], qs, MAGIC));
                    unsigned f2 = __float_as_uint(fmaf(acc[b][mt][2], qs, MAGIC));
                    unsigned f3 = __float_as_uint(fmaf(acc[b][mt][3], qs, MAGIC));
                    unsigned t01 = __builtin_amdgcn_perm(f1, f0, 0x00000400u);
                    unsigned t23 = __builtin_amdgcn_perm(f3, f2, 0x00000400u);
                    d[b * 2 + mt] = __builtin_amdgcn_perm(t23, t01, 0x05040100u);
                }
            }
            char* gp = tab + (size_t)cid * 128 + kg * 32;
            *(uint4*)gp        = make_uint4(d[0], d[1], d[2], d[3]);
            *(uint4*)(gp + 16) = make_uint4(d[4], d[5], d[6], d[7]);
            if (kg == 0) scl[cid] = m * (1.0f / 127.0f);
        }
    }

    // ---- part 2: dense root GEMM + bias, mt range split across y ----
    {
        const int mt0 = ybit * 4;
#pragma unroll 2
        for (int mt = mt0; mt < mt0 + 4; ++mt) {
            const int col0 = mt * 16 + kg * 4;
            f4v acc = *(const f4v*)&bias[col0];
#pragma unroll
            for (int kc = 0; kc < 4; ++kc) {
                s8v afrag = *(const s8v*)&RB[(((mt * 4 + kc) * 4 + kg) * 16 + lm) * 8];
                acc = __builtin_amdgcn_mfma_f32_16x16x32_bf16(afrag, bfr[kc], acc, 0, 0, 0);
            }
            if (OUT_BF16) {
                unsigned int p0 = (unsigned int)f2bfbits(acc[0]) |
                                  ((unsigned int)f2bfbits(acc[1]) << 16);
                unsigned int p1 = (unsigned int)f2bfbits(acc[2]) |
                                  ((unsigned int)f2bfbits(acc[3]) << 16);
                *(uint2*)((ushort*)outv + (size_t)node * DIM + col0) = make_uint2(p0, p1);
            } else {
                *(f4v*)((float*)outv + (size_t)node * DIM + col0) = acc;
            }
        }
    }
}

// ---------------------------------------------------------------------------
// Edge-stream aggregate over compact int8 table. Half-wave per dst node;
// start/end from segd cursors (post-scatter: cursor = local start + cnt).
// ---------------------------------------------------------------------------
template<bool OUT_BF16>
__global__ __launch_bounds__(256) void agg8_kernel(const int2* __restrict__ evec,
                                                   const int2* __restrict__ segd,
                                                   const int2* __restrict__ bsum,
                                                   const char* __restrict__ tab,
                                                   const float* __restrict__ scl,
                                                   void* __restrict__ outv) {
    const int hw = threadIdx.x >> 5;
    const int o  = threadIdx.x & 31;
    const int v  = blockIdx.x * 8 + hw;

    const int ei = v * N_REL + N_REL - 1;
    const int end = segd[ei].x + bsum[ei >> 10].x;
    int start = 0;
    if (v > 0) {
        const int si = v * N_REL - 1;
        start = segd[si].x + bsum[si >> 10].x;
    }

    const int p = o >> 4;            // edge parity within the quad (0/1)
    const int w = o & 15;            // 8-byte sub-chunk of the 128B row

    float acc[8];
#pragma unroll
    for (int j = 0; j < 8; ++j) acc[j] = 0.f;

#pragma unroll 2
    for (int base = start; base < end; base += 4) {
        const int k0 = base + p;
        const int k1 = base + 2 + p;
        const int2 e0 = evec[min(k0, end - 1)];
        const int2 e1 = evec[min(k1, end - 1)];
        const int g0 = e0.x, g1 = e1.x;
        const float i0 = (k0 < end) ? __int_as_float(e0.y) : 0.f;
        const float i1 = (k1 < end) ? __int_as_float(e1.y) : 0.f;
        const uint2 q0 = *(const uint2*)(tab + (size_t)g0 * 128 + w * 8);
        const uint2 q1 = *(const uint2*)(tab + (size_t)g1 * 128 + w * 8);
        const float s0 = scl[g0] * i0;
        const float s1 = scl[g1] * i1;
#pragma unroll
        for (int j = 0; j < 4; ++j) {
            acc[j]     = fmaf((float)(int)(signed char)(q0.x >> (8 * j)), s0, acc[j]);
            acc[4 + j] = fmaf((float)(int)(signed char)(q0.y >> (8 * j)), s0, acc[4 + j]);
        }
#pragma unroll
        for (int j = 0; j < 4; ++j) {
            acc[j]     = fmaf((float)(int)(signed char)(q1.x >> (8 * j)), s1, acc[j]);
            acc[4 + j] = fmaf((float)(int)(signed char)(q1.y >> (8 * j)), s1, acc[4 + j]);
        }
    }
#pragma unroll
    for (int j = 0; j < 8; ++j)
        acc[j] += __shfl_xor(acc[j], 16, 32);

    if (o < 16) {
        const int base0 = (o & 3) * 32 + (o >> 2) * 4;     // dim of acc[0]
        if (OUT_BF16) {
            ushort* hp = (ushort*)outv + (size_t)v * DIM + base0;
            ushort4 a0 = *(ushort4*)hp;
            ushort4 a1 = *(ushort4*)(hp + 16);
            a0.x = f2bfbits(bf2f(a0.x) + acc[0]);
            a0.y = f2bfbits(bf2f(a0.y) + acc[1]);
            a0.z = f2bfbits(bf2f(a0.z) + acc[2]);
            a0.w = f2bfbits(bf2f(a0.w) + acc[3]);
            a1.x = f2bfbits(bf2f(a1.x) + acc[4]);
            a1.y = f2bfbits(bf2f(a1.y) + acc[5]);
            a1.z = f2bfbits(bf2f(a1.z) + acc[6]);
            a1.w = f2bfbits(bf2f(a1.w) + acc[7]);
            *(ushort4*)hp        = a0;
            *(ushort4*)(hp + 16) = a1;
        } else {
            float* op = (float*)outv + (size_t)v * DIM + base0;
            float4 r0 = *(float4*)op;
            float4 r1 = *(float4*)(op + 16);
            r0.x += acc[0]; r0.y += acc[1]; r0.z += acc[2]; r0.w += acc[3];
            r1.x += acc[4]; r1.y += acc[5]; r1.z += acc[6]; r1.w += acc[7];
            *(float4*)op        = r0;
            *(float4*)(op + 16) = r1;
        }
    }
}

// ---------------------------------------------------------------------------
// Slow fallback (tiny ws): fp32 dense + gather-aggregate on x directly.
// ---------------------------------------------------------------------------
__global__ __launch_bounds__(256) void count_fb_kernel(const int* __restrict__ dst,
                                                       const int* __restrict__ et,
                                                       int* __restrict__ cnt, int E) {
    int e = blockIdx.x * 256 + threadIdx.x;
    if (e < E) atomicAdd(&cnt[dst[e] * N_REL + et[e]], 1);
}

template<bool RELU>
__global__ __launch_bounds__(256) void dense_old_kernel(const float* __restrict__ x,
                                                        const float* __restrict__ root,
                                                        const float* __restrict__ bias,
                                                        float* __restrict__ out) {
    const int wv = threadIdx.x >> 6;
    const int l  = threadIdx.x & 63;
    const int wt = blockIdx.x * 4 + wv;
    if (wt >= NWT) return;
    const int nbase = wt * 16;
    const int lm = l & 15;
    const int kg = l >> 4;
    const int node = nbase + lm;

    s8v bfr[4];
#pragma unroll
    for (int kc = 0; kc < 4; ++kc) {
        const float* xp = &x[(size_t)node * DIM + kc * BS + kg * 8];
#pragma unroll
        for (int i = 0; i < 8; ++i) {
            float v = xp[i];
            if (RELU) v = fmaxf(v, 0.f);
            bfr[kc][i] = (short)f2bfbits(v);
        }
    }
#pragma unroll 2
    for (int mt = 0; mt < 8; ++mt) {
        const int col0 = mt * 16 + kg * 4;
        f4v acc = *(const f4v*)&bias[col0];
#pragma unroll
        for (int kc = 0; kc < 4; ++kc) {
            const float* rp = &root[(size_t)(kc * BS + kg * 8) * DIM + mt * 16 + lm];
            s8v afrag;
#pragma unroll
            for (int i = 0; i < 8; ++i)
                afrag[i] = (short)f2bfbits(rp[i * DIM]);
            acc = __builtin_amdgcn_mfma_f32_16x16x32_bf16(afrag, bfr[kc], acc, 0, 0, 0);
        }
        *(f4v*)&out[(size_t)node * DIM + col0] = acc;
    }
}

template<bool RELU>
__global__ __launch_bounds__(256) void agg_fallback_kernel(const int* __restrict__ srcs,
                                                           const int* __restrict__ off,
                                                           const int* __restrict__ cnt,
                                                           const float* __restrict__ x,
                                                           const float* __restrict__ W,
                                                           float* __restrict__ out) {
    __shared__ float Wsh[N_REL * BS * BS];
    const int bblk = blockIdx.y;
    for (int idx = threadIdx.x * 4; idx < N_REL * BS * BS; idx += 1024) {
        int r = idx >> 10, rest = idx & 1023;
        *(float4*)&Wsh[idx] = *(const float4*)&W[(r * NBLK + bblk) * 1024 + rest];
    }
    __syncthreads();
    const int hw = threadIdx.x >> 5;
    const int o  = threadIdx.x & 31;
    const int v  = blockIdx.x * 8 + hw;
    int endv = 0, cv = 0;
    if (o < N_REL) { endv = off[v * N_REL + o]; cv = cnt[v * N_REL + o]; }
    float acc = out[v * DIM + bblk * BS + o];
    for (int r = 0; r < N_REL; ++r) {
        const int c = __shfl(cv, r, 32);
        if (c == 0) continue;
        const int end = __shfl(endv, r, 32);
        float xs = 0.f;
        for (int k = end - c; k < end; ++k) {
            const int s = srcs[k];
            float xv = x[s * DIM + bblk * BS + o];
            if (RELU) xv = fmaxf(xv, 0.f);
            xs += xv;
        }
        xs *= (1.0f / (float)c);
        const float* wr = &Wsh[r * (BS * BS)];
#pragma unroll
        for (int i = 0; i < BS; i += 2) {
            float xi0 = __shfl(xs, i, 32);
            float xi1 = __shfl(xs, i + 1, 32);
            acc = fmaf(xi0, wr[i * BS + o], acc);
            acc = fmaf(xi1, wr[(i + 1) * BS + o], acc);
        }
    }
    out[v * DIM + bblk * BS + o] = acc;
}

// ---------------------------------------------------------------------------
extern "C" void kernel_launch(void* const* d_in, const int* in_sizes, int n_in,
                              void* d_out, int out_size, void* d_ws, size_t ws_size,
                              hipStream_t stream) {
    const int*   edge_index = (const int*)d_in[0];
    const int*   src   = edge_index;
    const int*   dstv  = edge_index + N_EDGES;
    const int*   et    = (const int*)d_in[1];
    const float* x0    = (const float*)d_in[2];
    const float* W1    = (const float*)d_in[3];
    const float* root1 = (const float*)d_in[4];
    const float* bias1 = (const float*)d_in[5];
    const float* W2    = (const float*)d_in[6];
    const float* root2 = (const float*)d_in[7];
    const float* bias2 = (const float*)d_in[8];
    float* out = (float*)d_out;

    // ---- fast-path workspace layout (141.4 MB total) ----
    char* ws = (char*)d_ws;
    ushort* h    = (ushort*)ws;                             // 12,800,000 (bf16)
    int*    cnt  = (int*)   (ws + 12800000);                //  3,200,000
    int*    used = (int*)   (ws + 16000000);                //  3,200,000 (adj to cnt)
    int*    cmap = (int*)   (ws + 19200000);                //  3,200,000
    int2*   segd = (int2*)  (ws + 22400000);                //  6,400,000
    int2*   evec = (int2*)  (ws + 28800000);                //  6,400,000
    int2*   bsum = (int2*)  (ws + 35200000);                //      8,192
    ushort* WB1  = (ushort*)(ws + 35208192);                //    262,144
    ushort* WB2  = (ushort*)(ws + 35470336);                //    262,144
    ushort* RB1  = (ushort*)(ws + 35732480);                //     32,768
    ushort* RB2  = (ushort*)(ws + 35765248);                //     32,768
    float*  scl  = (float*) (ws + 35798016);                //  3,200,000
    char*   tab  =          (ws + 38998016);                // 102,400,000
    const size_t FAST_NEED = 141398016ull;

    const int egrid = (N_EDGES + 255) / 256;     // 3125

    if (ws_size >= FAST_NEED) {
        prep_kernel<<<1152, 256, 0, stream>>>(W1, W2, root1, root2, WB1, WB2,
                                              RB1, RB2, (uint4*)cnt);
        count_kernel<<<egrid, 256, 0, stream>>>(src, dstv, et, cnt, used, N_EDGES);
        scan1j_kernel<<<N_SCAN_BLKS, 256, 0, stream>>>(cnt, used, segd, cmap, bsum, NSEG);
        scan2j_kernel<<<1, 1024, 0, stream>>>(bsum, N_SCAN_BLKS);

        const int ngrid = N_NODES / 8;           // 6250

        // ---- layer 1: INTERLEAVED scatter+fused transform+dense ----
        fused_kernel<false, true, false, true><<<SCATB + 2 * NWTB, 256, 0, stream>>>(
            x0, WB1, RB1, bias1, used, cmap, bsum, tab, scl, h,
            src, dstv, et, segd, evec);
        agg8_kernel<true><<<ngrid, 256, 0, stream>>>(evec, segd, bsum, tab, scl, h);

        // ---- layer 2: fused transform+dense ----
        fused_kernel<true, false, true, false><<<2 * NWTB, 256, 0, stream>>>(
            h, WB2, RB2, bias2, used, cmap, bsum, tab, scl, out,
            src, dstv, et, segd, evec);
        agg8_kernel<false><<<ngrid, 256, 0, stream>>>(evec, segd, bsum, tab, scl, out);
    } else {
        // ---- slow fallback (ws >= 35.3 MB): fp32 h + direct gather-agg ----
        float* hf    = (float*)d_ws;
        int*   cntf  = (int*)((char*)d_ws + 25600000);
        int*   offf  = (int*)((char*)d_ws + 28800000);
        int*   srcsf = (int*)((char*)d_ws + 32000000);
        int*   bsumf = (int*)((char*)d_ws + 35200000);

        hipMemsetAsync(cntf, 0, (size_t)NSEG * sizeof(int), stream);
        count_fb_kernel<<<egrid, 256, 0, stream>>>(dstv, et, cntf, N_EDGES);
        scan1_kernel<<<N_SCAN_BLKS, 256, 0, stream>>>(cntf, offf, bsumf, NSEG);
        scan2_kernel<<<1, 1024, 0, stream>>>(bsumf, N_SCAN_BLKS);
        scan3_kernel<<<(NSEG + 255) / 256, 256, 0, stream>>>(offf, bsumf, NSEG);
        scatter_old_kernel<<<egrid, 256, 0, stream>>>(src, dstv, et, offf, srcsf, N_EDGES);

        dim3 fgrid2(N_NODES / 8, NBLK);
        dense_old_kernel<false><<<NWTB, 256, 0, stream>>>(x0, root1, bias1, hf);
        agg_fallback_kernel<false><<<fgrid2, 256, 0, stream>>>(srcsf, offf, cntf, x0, W1, hf);
        dense_old_kernel<true><<<NWTB, 256, 0, stream>>>(hf, root2, bias2, out);
        agg_fallback_kernel<true><<<fgrid2, 256, 0, stream>>>(srcsf, offf, cntf, hf, W2, out);
    }
}

// Round 17
// 237.368 us; speedup vs baseline: 1.0631x; 1.0631x over previous
//
#include <hip/hip_runtime.h>
#include <hip/hip_bf16.h>

#define N_NODES 50000
#define N_REL   16
#define DIM     128
#define NBLK    4
#define BS      32
#define N_EDGES 800000
#define NSEG    (N_NODES * N_REL)
#define SCAN_BLK 1024
#define N_SCAN_BLKS ((NSEG + SCAN_BLK - 1) / SCAN_BLK)
#define NWT     (N_NODES / 16)        // 3125 wave-tiles of 16 nodes
#define NWTB    ((NWT + 3) / 4)       // 782 fused blocks per y-slice

typedef __attribute__((ext_vector_type(8))) short s8v;            // 8 bf16
typedef __attribute__((ext_vector_type(8))) unsigned short u8v;   // 8 bf16 bits
typedef __attribute__((ext_vector_type(4))) float f4v;            // mfma C/D

__device__ __forceinline__ float bf2f(unsigned short u) {
    return __uint_as_float(((unsigned int)u) << 16);
}
__device__ __forceinline__ unsigned short f2bfbits(float f) {   // RNE
    unsigned int u = __float_as_uint(f);
    return (unsigned short)((u + 0x7fffu + ((u >> 16) & 1u)) >> 16);
}

// ---------------------------------------------------------------------------
// Prep (+zero cnt/used): convert W/root to bf16 A-fragment lane order and
// grid-stride zero the 6.4MB cnt+used region (removes the memset dispatch).
// ---------------------------------------------------------------------------
__global__ __launch_bounds__(256) void prep_kernel(const float* __restrict__ W1,
                                                   const float* __restrict__ W2,
                                                   const float* __restrict__ r1,
                                                   const float* __restrict__ r2,
                                                   ushort* __restrict__ WB1,
                                                   ushort* __restrict__ WB2,
                                                   ushort* __restrict__ RB1,
                                                   ushort* __restrict__ RB2,
                                                   uint4* __restrict__ zero_base) {
    int t = blockIdx.x * 256 + threadIdx.x;
    // zero cnt+used: 2*NSEG ints = 400000 uint4s
    for (int i = t; i < (2 * NSEG) / 4; i += 1152 * 256)
        zero_base[i] = make_uint4(0u, 0u, 0u, 0u);

    if (t < 262144) {                               // WB1 / WB2
        const float* W = (t < 131072) ? W1 : W2;
        ushort* WB     = (t < 131072) ? WB1 : WB2;
        int idx = t & 131071;
        int i  = idx & 7;
        int lm = (idx >> 3) & 15;
        int kg = (idx >> 7) & 3;
        int mt = (idx >> 9) & 1;
        int b  = (idx >> 10) & 3;
        int r  = idx >> 12;
        WB[idx] = f2bfbits(W[((size_t)(r * 4 + b) * 32 + kg * 8 + i) * 32 + mt * 16 + lm]);
    } else if (t < 294912) {                        // RB1 / RB2
        int u = t - 262144;
        const float* R = (u < 16384) ? r1 : r2;
        ushort* RB     = (u < 16384) ? RB1 : RB2;
        int idx = u & 16383;
        int i  = idx & 7;
        int lm = (idx >> 3) & 15;
        int kg = (idx >> 7) & 3;
        int kc = (idx >> 9) & 3;
        int mt = (idx >> 11) & 7;
        RB[idx] = f2bfbits(R[(size_t)(kc * 32 + kg * 8 + i) * DIM + mt * 16 + lm]);
    }
}

// ---------------------------------------------------------------------------
// CSR build: count (+used flag) -> joint scan {cnt,used} (block-local; bsum
// applied by consumers) -> scatter (appended per-block inside fused1)
// ---------------------------------------------------------------------------
__global__ __launch_bounds__(256) void count_kernel(const int* __restrict__ src,
                                                    const int* __restrict__ dst,
                                                    const int* __restrict__ et,
                                                    int* __restrict__ cnt,
                                                    int* __restrict__ used, int E) {
    int e = blockIdx.x * 256 + threadIdx.x;
    if (e < E) {
        int r = et[e];
        atomicAdd(&cnt[dst[e] * N_REL + r], 1);
        used[r * N_NODES + src[e]] = 1;        // benign race, all write 1
    }
}

__global__ __launch_bounds__(256) void scan1j_kernel(const int* __restrict__ cnt,
                                                     const int* __restrict__ used,
                                                     int* __restrict__ off,
                                                     int* __restrict__ cmap,
                                                     int2* __restrict__ bsum, int M) {
    const int t = threadIdx.x;
    const int base = blockIdx.x * SCAN_BLK + t * 4;
    int c[4], u[4];
#pragma unroll
    for (int i = 0; i < 4; ++i) {
        int idx = base + i;
        c[i] = (idx < M) ? cnt[idx] : 0;
        u[i] = (idx < M) ? used[idx] : 0;
    }
    int cs = c[0] + c[1] + c[2] + c[3];
    int us = u[0] + u[1] + u[2] + u[3];
    const int lane = t & 63, wid = t >> 6;
    int cinc = cs, uinc = us;
    for (int d = 1; d < 64; d <<= 1) {
        int a = __shfl_up(cinc, d, 64);
        int b = __shfl_up(uinc, d, 64);
        if (lane >= d) { cinc += a; uinc += b; }
    }
    __shared__ int cw[5], uw[5];
    if (lane == 63) { cw[wid] = cinc; uw[wid] = uinc; }
    __syncthreads();
    if (t == 0) {
        int a = 0, b = 0;
        for (int w = 0; w < 4; ++w) {
            int x = cw[w]; cw[w] = a; a += x;
            int y = uw[w]; uw[w] = b; b += y;
        }
        cw[4] = a; uw[4] = b;
    }
    __syncthreads();
    int cex = cinc - cs + cw[wid];
    int uex = uinc - us + uw[wid];
#pragma unroll
    for (int i = 0; i < 4; ++i) {
        int idx = base + i;
        if (idx < M) { off[idx] = cex; cmap[idx] = uex; }
        cex += c[i]; uex += u[i];
    }
    if (t == 0) bsum[blockIdx.x] = make_int2(cw[4], uw[4]);
}

__global__ __launch_bounds__(1024) void scan2j_kernel(int2* __restrict__ bsum, int nb) {
    const int t = threadIdx.x;
    int2 s = (t < nb) ? bsum[t] : make_int2(0, 0);
    const int lane = t & 63, wid = t >> 6;
    int ci = s.x, ui = s.y;
    for (int d = 1; d < 64; d <<= 1) {
        int a = __shfl_up(ci, d, 64);
        int b = __shfl_up(ui, d, 64);
        if (lane >= d) { ci += a; ui += b; }
    }
    __shared__ int cw[16], uw[16];
    if (lane == 63) { cw[wid] = ci; uw[wid] = ui; }
    __syncthreads();
    if (t == 0) {
        int a = 0, b = 0;
        for (int w = 0; w < 16; ++w) {
            int x = cw[w]; cw[w] = a; a += x;
            int y = uw[w]; uw[w] = b; b += y;
        }
    }
    __syncthreads();
    if (t < nb) bsum[t] = make_int2(ci - s.x + cw[wid], ui - s.y + uw[wid]);
}

// slow-fallback scan (single array) + scatter (srcs list)
__global__ __launch_bounds__(256) void scan1_kernel(const int* __restrict__ in,
                                                    int* __restrict__ out,
                                                    int* __restrict__ bsum, int M) {
    const int t = threadIdx.x;
    const int base = blockIdx.x * SCAN_BLK + t * 4;
    int v0 = (base + 0 < M) ? in[base + 0] : 0;
    int v1 = (base + 1 < M) ? in[base + 1] : 0;
    int v2 = (base + 2 < M) ? in[base + 2] : 0;
    int v3 = (base + 3 < M) ? in[base + 3] : 0;
    const int s = v0 + v1 + v2 + v3;
    const int lane = t & 63, wid = t >> 6;
    int inc = s;
    for (int d = 1; d < 64; d <<= 1) {
        int u = __shfl_up(inc, d, 64);
        if (lane >= d) inc += u;
    }
    __shared__ int wsum[5];
    if (lane == 63) wsum[wid] = inc;
    __syncthreads();
    if (t == 0) {
        int a = 0;
        for (int w = 0; w < 4; ++w) { int u = wsum[w]; wsum[w] = a; a += u; }
        wsum[4] = a;
    }
    __syncthreads();
    const int ex = inc - s + wsum[wid];
    if (base + 0 < M) out[base + 0] = ex;
    if (base + 1 < M) out[base + 1] = ex + v0;
    if (base + 2 < M) out[base + 2] = ex + v0 + v1;
    if (base + 3 < M) out[base + 3] = ex + v0 + v1 + v2;
    if (t == 0) bsum[blockIdx.x] = wsum[4];
}

__global__ __launch_bounds__(1024) void scan2_kernel(int* __restrict__ bsum, int nb) {
    const int t = threadIdx.x;
    int s = (t < nb) ? bsum[t] : 0;
    const int lane = t & 63, wid = t >> 6;
    int inc = s;
    for (int d = 1; d < 64; d <<= 1) {
        int u = __shfl_up(inc, d, 64);
        if (lane >= d) inc += u;
    }
    __shared__ int wsum[16];
    if (lane == 63) wsum[wid] = inc;
    __syncthreads();
    if (t == 0) {
        int a = 0;
        for (int w = 0; w < 16; ++w) { int u = wsum[w]; wsum[w] = a; a += u; }
    }
    __syncthreads();
    const int ex = inc - s + wsum[wid];
    if (t < nb) bsum[t] = ex;
}

__global__ __launch_bounds__(256) void scan3_kernel(int* __restrict__ out,
                                                    const int* __restrict__ bsum, int M) {
    int i = blockIdx.x * 256 + threadIdx.x;
    if (i < M) out[i] += bsum[i / SCAN_BLK];
}

__global__ __launch_bounds__(256) void scatter_old_kernel(const int* __restrict__ src,
                                                          const int* __restrict__ dst,
                                                          const int* __restrict__ et,
                                                          int* __restrict__ off,
                                                          int* __restrict__ srcs, int E) {
    int e = blockIdx.x * 256 + threadIdx.x;
    if (e < E) {
        int seg = dst[e] * N_REL + et[e];
        int pos = atomicAdd(&off[seg], 1);
        srcs[pos] = src[e];
    }
}

// ---------------------------------------------------------------------------
// FUSED transform. Round-14 structure: relation-split (8 rels per y-slice),
// tree rowmax, magic-rounding int8 quantize, compact table; dense root GEMM
// split across y (mt 0-3 / 4-7). WITH_SCATTER: each block ALSO scatters its
// own 512-edge chunk at the tail -- scatter work is spread uniformly through
// the dispatch, overlapping later blocks' compute at wave granularity.
// ---------------------------------------------------------------------------
template<bool IN_BF16, bool OUT_BF16, bool RELU, bool WITH_SCATTER>
__global__ __launch_bounds__(256) void fused_kernel(const void* __restrict__ xin,
                                                    const ushort* __restrict__ WB,
                                                    const ushort* __restrict__ RB,
                                                    const float* __restrict__ bias,
                                                    const int* __restrict__ used,
                                                    const int* __restrict__ cmap,
                                                    const int2* __restrict__ bsum,
                                                    char* __restrict__ tab,
                                                    float* __restrict__ scl,
                                                    void* __restrict__ outv,
                                                    const int* __restrict__ src,
                                                    const int* __restrict__ dstv,
                                                    const int* __restrict__ et,
                                                    int* __restrict__ off,
                                                    const int* __restrict__ cnt,
                                                    int2* __restrict__ evec) {
    const int fid  = blockIdx.x;
    const int ybit = (fid >= NWTB) ? 1 : 0;
    const int xb   = fid - ybit * NWTB;
    const int wv = threadIdx.x >> 6;
    const int l  = threadIdx.x & 63;
    const int wt = xb * 4 + wv;
    const int lm = l & 15;
    const int kg = l >> 4;
    const int node = wt * 16 + lm;

    if (wt < NWT) {
        // x row fragments for all 4 K-blocks (shared by both parts)
        s8v bfr[4];
#pragma unroll
        for (int b = 0; b < 4; ++b) {
            if (IN_BF16) {
                const ushort* xp = (const ushort*)xin + (size_t)node * DIM + b * BS + kg * 8;
                u8v u = *(const u8v*)xp;
#pragma unroll
                for (int i = 0; i < 8; ++i) {
                    unsigned short us = u[i];
                    if (RELU) us = (us & 0x8000u) ? (unsigned short)0 : us;
                    bfr[b][i] = (short)us;
                }
            } else {
                const float* xp = (const float*)xin + (size_t)node * DIM + b * BS + kg * 8;
#pragma unroll
                for (int i = 0; i < 8; ++i) {
                    float v = xp[i];
                    if (RELU) v = fmaxf(v, 0.f);
                    bfr[b][i] = (short)f2bfbits(v);
                }
            }
        }

        // ---- part 1: int8 message table, 8 relations for this y ----
        const int rbase = ybit * 8;
        const float MAGIC = 12582912.0f;   // 1.5*2^23: low byte = int8(RNE(x))
#pragma unroll 2
        for (int ri = 0; ri < 8; ++ri) {
            const int rr = rbase + ri;
            const int grow = rr * N_NODES + node;
            const int flag = used[grow];            // hoisted loads
            const int cid  = cmap[grow] + bsum[grow >> 10].y;
            f4v acc[4][2];
#pragma unroll
            for (int b = 0; b < 4; ++b) {
#pragma unroll
                for (int mt = 0; mt < 2; ++mt) {
                    s8v afrag = *(const s8v*)&WB[((((rr * 4 + b) * 2 + mt) * 4 + kg) * 16 + lm) * 8];
                    f4v z = {0.f, 0.f, 0.f, 0.f};
                    acc[b][mt] = __builtin_amdgcn_mfma_f32_16x16x32_bf16(afrag, bfr[b], z, 0, 0, 0);
                }
            }
            // rowmax: depth-5 tree over 32 in-lane values, then 2 shfl_xor
            float t8[8];
#pragma unroll
            for (int b = 0; b < 4; ++b)
#pragma unroll
                for (int mt = 0; mt < 2; ++mt)
                    t8[b * 2 + mt] = fmaxf(fmaxf(fabsf(acc[b][mt][0]), fabsf(acc[b][mt][1])),
                                           fmaxf(fabsf(acc[b][mt][2]), fabsf(acc[b][mt][3])));
            float m = fmaxf(fmaxf(fmaxf(t8[0], t8[1]), fmaxf(t8[2], t8[3])),
                            fmaxf(fmaxf(t8[4], t8[5]), fmaxf(t8[6], t8[7])));
            m = fmaxf(m, __shfl_xor(m, 16, 64));
            m = fmaxf(m, __shfl_xor(m, 32, 64));
            m = fmaxf(m, 1e-30f);

            if (flag) {
                const float qs = 127.0f / m;
                unsigned int d[8];
#pragma unroll
                for (int b = 0; b < 4; ++b) {
#pragma unroll
                    for (int mt = 0; mt < 2; ++mt) {
                        unsigned f0 = __float_as_uint(fmaf(acc[b][mt][0], qs, MAGIC));
                        unsigned f1 = __float_as_uint(fmaf(acc[b][mt][1], qs, MAGIC));
                        unsigned f2 = __float_as_uint(fmaf(acc[b][mt][2], qs, MAGIC));
                        unsigned f3 = __float_as_uint(fmaf(acc[b][mt][3], qs, MAGIC));
                        unsigned t01 = __builtin_amdgcn_perm(f1, f0, 0x00000400u);
                        unsigned t23 = __builtin_amdgcn_perm(f3, f2, 0x00000400u);
                        d[b * 2 + mt] = __builtin_amdgcn_perm(t23, t01, 0x05040100u);
                    }
                }
                char* gp = tab + (size_t)cid * 128 + kg * 32;
                *(uint4*)gp        = make_uint4(d[0], d[1], d[2], d[3]);
                *(uint4*)(gp + 16) = make_uint4(d[4], d[5], d[6], d[7]);
                if (kg == 0) scl[cid] = m * (1.0f / 127.0f);
            }
        }

        // ---- part 2: dense root GEMM + bias, mt range split across y ----
        {
            const int mt0 = ybit * 4;
#pragma unroll 2
            for (int mt = mt0; mt < mt0 + 4; ++mt) {
                const int col0 = mt * 16 + kg * 4;
                f4v acc = *(const f4v*)&bias[col0];
#pragma unroll
                for (int kc = 0; kc < 4; ++kc) {
                    s8v afrag = *(const s8v*)&RB[(((mt * 4 + kc) * 4 + kg) * 16 + lm) * 8];
                    acc = __builtin_amdgcn_mfma_f32_16x16x32_bf16(afrag, bfr[kc], acc, 0, 0, 0);
                }
                if (OUT_BF16) {
                    unsigned int p0 = (unsigned int)f2bfbits(acc[0]) |
                                      ((unsigned int)f2bfbits(acc[1]) << 16);
                    unsigned int p1 = (unsigned int)f2bfbits(acc[2]) |
                                      ((unsigned int)f2bfbits(acc[3]) << 16);
                    *(uint2*)((ushort*)outv + (size_t)node * DIM + col0) = make_uint2(p0, p1);
                } else {
                    *(f4v*)((float*)outv + (size_t)node * DIM + col0) = acc;
                }
            }
        }
    }

    // ---- part 3 (WITH_SCATTER): this block's 512-edge scatter chunk ----
    if (WITH_SCATTER) {
        const int e0 = fid * 512 + threadIdx.x;
#pragma unroll
        for (int q = 0; q < 2; ++q) {
            const int e = e0 + q * 256;
            if (e < N_EDGES) {
                int r = et[e];
                int seg = dstv[e] * N_REL + r;
                int pos = atomicAdd(&off[seg], 1) + bsum[seg >> 10].x;
                float inv = 1.0f / (float)cnt[seg];
                int grow = r * N_NODES + src[e];
                int g = cmap[grow] + bsum[grow >> 10].y;
                evec[pos] = make_int2(g, __float_as_int(inv));
            }
        }
    }
}

// ---------------------------------------------------------------------------
// Edge-stream aggregate over compact int8 table. Half-wave per dst node;
// start/end from block-local off + bsum (off holds segment ENDs post-scatter).
// ---------------------------------------------------------------------------
template<bool OUT_BF16>
__global__ __launch_bounds__(256) void agg8_kernel(const int2* __restrict__ evec,
                                                   const int* __restrict__ off,
                                                   const int2* __restrict__ bsum,
                                                   const char* __restrict__ tab,
                                                   const float* __restrict__ scl,
                                                   void* __restrict__ outv) {
    const int hw = threadIdx.x >> 5;
    const int o  = threadIdx.x & 31;
    const int v  = blockIdx.x * 8 + hw;

    const int ei = v * N_REL + N_REL - 1;
    const int end = off[ei] + bsum[ei >> 10].x;
    int start = 0;
    if (v > 0) {
        const int si = v * N_REL - 1;
        start = off[si] + bsum[si >> 10].x;
    }

    const int p = o >> 4;            // edge parity within the quad (0/1)
    const int w = o & 15;            // 8-byte sub-chunk of the 128B row

    float acc[8];
#pragma unroll
    for (int j = 0; j < 8; ++j) acc[j] = 0.f;

#pragma unroll 2
    for (int base = start; base < end; base += 4) {
        const int k0 = base + p;
        const int k1 = base + 2 + p;
        const int2 e0 = evec[min(k0, end - 1)];
        const int2 e1 = evec[min(k1, end - 1)];
        const int g0 = e0.x, g1 = e1.x;
        const float i0 = (k0 < end) ? __int_as_float(e0.y) : 0.f;
        const float i1 = (k1 < end) ? __int_as_float(e1.y) : 0.f;
        const uint2 q0 = *(const uint2*)(tab + (size_t)g0 * 128 + w * 8);
        const uint2 q1 = *(const uint2*)(tab + (size_t)g1 * 128 + w * 8);
        const float s0 = scl[g0] * i0;
        const float s1 = scl[g1] * i1;
#pragma unroll
        for (int j = 0; j < 4; ++j) {
            acc[j]     = fmaf((float)(int)(signed char)(q0.x >> (8 * j)), s0, acc[j]);
            acc[4 + j] = fmaf((float)(int)(signed char)(q0.y >> (8 * j)), s0, acc[4 + j]);
        }
#pragma unroll
        for (int j = 0; j < 4; ++j) {
            acc[j]     = fmaf((float)(int)(signed char)(q1.x >> (8 * j)), s1, acc[j]);
            acc[4 + j] = fmaf((float)(int)(signed char)(q1.y >> (8 * j)), s1, acc[4 + j]);
        }
    }
#pragma unroll
    for (int j = 0; j < 8; ++j)
        acc[j] += __shfl_xor(acc[j], 16, 32);

    if (o < 16) {
        const int base0 = (o & 3) * 32 + (o >> 2) * 4;     // dim of acc[0]
        if (OUT_BF16) {
            ushort* hp = (ushort*)outv + (size_t)v * DIM + base0;
            ushort4 a0 = *(ushort4*)hp;
            ushort4 a1 = *(ushort4*)(hp + 16);
            a0.x = f2bfbits(bf2f(a0.x) + acc[0]);
            a0.y = f2bfbits(bf2f(a0.y) + acc[1]);
            a0.z = f2bfbits(bf2f(a0.z) + acc[2]);
            a0.w = f2bfbits(bf2f(a0.w) + acc[3]);
            a1.x = f2bfbits(bf2f(a1.x) + acc[4]);
            a1.y = f2bfbits(bf2f(a1.y) + acc[5]);
            a1.z = f2bfbits(bf2f(a1.z) + acc[6]);
            a1.w = f2bfbits(bf2f(a1.w) + acc[7]);
            *(ushort4*)hp        = a0;
            *(ushort4*)(hp + 16) = a1;
        } else {
            float* op = (float*)outv + (size_t)v * DIM + base0;
            float4 r0 = *(float4*)op;
            float4 r1 = *(float4*)(op + 16);
            r0.x += acc[0]; r0.y += acc[1]; r0.z += acc[2]; r0.w += acc[3];
            r1.x += acc[4]; r1.y += acc[5]; r1.z += acc[6]; r1.w += acc[7];
            *(float4*)op        = r0;
            *(float4*)(op + 16) = r1;
        }
    }
}

// ---------------------------------------------------------------------------
// Slow fallback (tiny ws): fp32 dense + gather-aggregate on x directly.
// ---------------------------------------------------------------------------
__global__ __launch_bounds__(256) void count_fb_kernel(const int* __restrict__ dst,
                                                       const int* __restrict__ et,
                                                       int* __restrict__ cnt, int E) {
    int e = blockIdx.x * 256 + threadIdx.x;
    if (e < E) atomicAdd(&cnt[dst[e] * N_REL + et[e]], 1);
}

template<bool RELU>
__global__ __launch_bounds__(256) void dense_old_kernel(const float* __restrict__ x,
                                                        const float* __restrict__ root,
                                                        const float* __restrict__ bias,
                                                        float* __restrict__ out) {
    const int wv = threadIdx.x >> 6;
    const int l  = threadIdx.x & 63;
    const int wt = blockIdx.x * 4 + wv;
    if (wt >= NWT) return;
    const int nbase = wt * 16;
    const int lm = l & 15;
    const int kg = l >> 4;
    const int node = nbase + lm;

    s8v bfr[4];
#pragma unroll
    for (int kc = 0; kc < 4; ++kc) {
        const float* xp = &x[(size_t)node * DIM + kc * BS + kg * 8];
#pragma unroll
        for (int i = 0; i < 8; ++i) {
            float v = xp[i];
            if (RELU) v = fmaxf(v, 0.f);
            bfr[kc][i] = (short)f2bfbits(v);
        }
    }
#pragma unroll 2
    for (int mt = 0; mt < 8; ++mt) {
        const int col0 = mt * 16 + kg * 4;
        f4v acc = *(const f4v*)&bias[col0];
#pragma unroll
        for (int kc = 0; kc < 4; ++kc) {
            const float* rp = &root[(size_t)(kc * BS + kg * 8) * DIM + mt * 16 + lm];
            s8v afrag;
#pragma unroll
            for (int i = 0; i < 8; ++i)
                afrag[i] = (short)f2bfbits(rp[i * DIM]);
            acc = __builtin_amdgcn_mfma_f32_16x16x32_bf16(afrag, bfr[kc], acc, 0, 0, 0);
        }
        *(f4v*)&out[(size_t)node * DIM + col0] = acc;
    }
}

template<bool RELU>
__global__ __launch_bounds__(256) void agg_fallback_kernel(const int* __restrict__ srcs,
                                                           const int* __restrict__ off,
                                                           const int* __restrict__ cnt,
                                                           const float* __restrict__ x,
                                                           const float* __restrict__ W,
                                                           float* __restrict__ out) {
    __shared__ float Wsh[N_REL * BS * BS];
    const int bblk = blockIdx.y;
    for (int idx = threadIdx.x * 4; idx < N_REL * BS * BS; idx += 1024) {
        int r = idx >> 10, rest = idx & 1023;
        *(float4*)&Wsh[idx] = *(const float4*)&W[(r * NBLK + bblk) * 1024 + rest];
    }
    __syncthreads();
    const int hw = threadIdx.x >> 5;
    const int o  = threadIdx.x & 31;
    const int v  = blockIdx.x * 8 + hw;
    int endv = 0, cv = 0;
    if (o < N_REL) { endv = off[v * N_REL + o]; cv = cnt[v * N_REL + o]; }
    float acc = out[v * DIM + bblk * BS + o];
    for (int r = 0; r < N_REL; ++r) {
        const int c = __shfl(cv, r, 32);
        if (c == 0) continue;
        const int end = __shfl(endv, r, 32);
        float xs = 0.f;
        for (int k = end - c; k < end; ++k) {
            const int s = srcs[k];
            float xv = x[s * DIM + bblk * BS + o];
            if (RELU) xv = fmaxf(xv, 0.f);
            xs += xv;
        }
        xs *= (1.0f / (float)c);
        const float* wr = &Wsh[r * (BS * BS)];
#pragma unroll
        for (int i = 0; i < BS; i += 2) {
            float xi0 = __shfl(xs, i, 32);
            float xi1 = __shfl(xs, i + 1, 32);
            acc = fmaf(xi0, wr[i * BS + o], acc);
            acc = fmaf(xi1, wr[(i + 1) * BS + o], acc);
        }
    }
    out[v * DIM + bblk * BS + o] = acc;
}

// ---------------------------------------------------------------------------
extern "C" void kernel_launch(void* const* d_in, const int* in_sizes, int n_in,
                              void* d_out, int out_size, void* d_ws, size_t ws_size,
                              hipStream_t stream) {
    const int*   edge_index = (const int*)d_in[0];
    const int*   src   = edge_index;
    const int*   dstv  = edge_index + N_EDGES;
    const int*   et    = (const int*)d_in[1];
    const float* x0    = (const float*)d_in[2];
    const float* W1    = (const float*)d_in[3];
    const float* root1 = (const float*)d_in[4];
    const float* bias1 = (const float*)d_in[5];
    const float* W2    = (const float*)d_in[6];
    const float* root2 = (const float*)d_in[7];
    const float* bias2 = (const float*)d_in[8];
    float* out = (float*)d_out;

    // ---- fast-path workspace layout (138.2 MB total; round-14 proven) ----
    char* ws = (char*)d_ws;
    ushort* h    = (ushort*)ws;                             // 12,800,000 (bf16)
    int*    cnt  = (int*)   (ws + 12800000);                //  3,200,000
    int*    used = (int*)   (ws + 16000000);                //  3,200,000 (adj to cnt)
    int*    off  = (int*)   (ws + 19200000);                //  3,200,000
    int*    cmap = (int*)   (ws + 22400000);                //  3,200,000
    int2*   evec = (int2*)  (ws + 25600000);                //  6,400,000
    int2*   bsum = (int2*)  (ws + 32000000);                //      8,192
    ushort* WB1  = (ushort*)(ws + 32008192);                //    262,144
    ushort* WB2  = (ushort*)(ws + 32270336);                //    262,144
    ushort* RB1  = (ushort*)(ws + 32532480);                //     32,768
    ushort* RB2  = (ushort*)(ws + 32565248);                //     32,768
    float*  scl  = (float*) (ws + 32598016);                //  3,200,000
    char*   tab  =          (ws + 35798016);                // 102,400,000
    const size_t FAST_NEED = 138198016ull;

    const int egrid = (N_EDGES + 255) / 256;     // 3125

    if (ws_size >= FAST_NEED) {
        prep_kernel<<<1152, 256, 0, stream>>>(W1, W2, root1, root2, WB1, WB2,
                                              RB1, RB2, (uint4*)cnt);
        count_kernel<<<egrid, 256, 0, stream>>>(src, dstv, et, cnt, used, N_EDGES);
        scan1j_kernel<<<N_SCAN_BLKS, 256, 0, stream>>>(cnt, used, off, cmap, bsum, NSEG);
        scan2j_kernel<<<1, 1024, 0, stream>>>(bsum, N_SCAN_BLKS);

        const int ngrid = N_NODES / 8;           // 6250

        // ---- layer 1: fused transform+dense with per-block scatter tail ----
        fused_kernel<false, true, false, true><<<2 * NWTB, 256, 0, stream>>>(
            x0, WB1, RB1, bias1, used, cmap, bsum, tab, scl, h,
            src, dstv, et, off, cnt, evec);
        agg8_kernel<true><<<ngrid, 256, 0, stream>>>(evec, off, bsum, tab, scl, h);

        // ---- layer 2: fused transform+dense ----
        fused_kernel<true, false, true, false><<<2 * NWTB, 256, 0, stream>>>(
            h, WB2, RB2, bias2, used, cmap, bsum, tab, scl, out,
            src, dstv, et, off, cnt, evec);
        agg8_kernel<false><<<ngrid, 256, 0, stream>>>(evec, off, bsum, tab, scl, out);
    } else {
        // ---- slow fallback (ws >= 35.3 MB): fp32 h + direct gather-agg ----
        float* hf    = (float*)d_ws;
        int*   cntf  = (int*)((char*)d_ws + 25600000);
        int*   offf  = (int*)((char*)d_ws + 28800000);
        int*   srcsf = (int*)((char*)d_ws + 32000000);
        int*   bsumf = (int*)((char*)d_ws + 35200000);

        hipMemsetAsync(cntf, 0, (size_t)NSEG * sizeof(int), stream);
        count_fb_kernel<<<egrid, 256, 0, stream>>>(dstv, et, cntf, N_EDGES);
        scan1_kernel<<<N_SCAN_BLKS, 256, 0, stream>>>(cntf, offf, bsumf, NSEG);
        scan2_kernel<<<1, 1024, 0, stream>>>(bsumf, N_SCAN_BLKS);
        scan3_kernel<<<(NSEG + 255) / 256, 256, 0, stream>>>(offf, bsumf, NSEG);
        scatter_old_kernel<<<egrid, 256, 0, stream>>>(src, dstv, et, offf, srcsf, N_EDGES);

        dim3 fgrid2(N_NODES / 8, NBLK);
        dense_old_kernel<false><<<NWTB, 256, 0, stream>>>(x0, root1, bias1, hf);
        agg_fallback_kernel<false><<<fgrid2, 256, 0, stream>>>(srcsf, offf, cntf, x0, W1, hf);
        dense_old_kernel<true><<<NWTB, 256, 0, stream>>>(hf, root2, bias2, out);
        agg_fallback_kernel<true><<<fgrid2, 256, 0, stream>>>(srcsf, offf, cntf, hf, W2, out);
    }
}

// Round 18
// 229.764 us; speedup vs baseline: 1.0983x; 1.0331x over previous
//
#include <hip/hip_runtime.h>
#include <hip/hip_bf16.h>

#define N_NODES 50000
#define N_REL   16
#define DIM     128
#define NBLK    4
#define BS      32
#define N_EDGES 800000
#define NSEG    (N_NODES * N_REL)
#define SCAN_BLK 1024
#define N_SCAN_BLKS ((NSEG + SCAN_BLK - 1) / SCAN_BLK)
#define NWT     (N_NODES / 16)        // 3125 wave-tiles of 16 nodes
#define NWTB    ((NWT + 3) / 4)       // 782 fused blocks per y-slice
#define SCATB   ((N_EDGES + 511) / 512)  // 1563 scatter blocks (2 edges/thread)

typedef __attribute__((ext_vector_type(8))) short s8v;            // 8 bf16
typedef __attribute__((ext_vector_type(8))) unsigned short u8v;   // 8 bf16 bits
typedef __attribute__((ext_vector_type(4))) float f4v;            // mfma C/D

__device__ __forceinline__ float bf2f(unsigned short u) {
    return __uint_as_float(((unsigned int)u) << 16);
}
__device__ __forceinline__ unsigned short f2bfbits(float f) {   // RNE
    unsigned int u = __float_as_uint(f);
    return (unsigned short)((u + 0x7fffu + ((u >> 16) & 1u)) >> 16);
}

// ---------------------------------------------------------------------------
// Prep (+zero cnt/used): convert W/root to bf16 A-fragment lane order and
// grid-stride zero the 6.4MB cnt+used region (removes the memset dispatch).
// ---------------------------------------------------------------------------
__global__ __launch_bounds__(256) void prep_kernel(const float* __restrict__ W1,
                                                   const float* __restrict__ W2,
                                                   const float* __restrict__ r1,
                                                   const float* __restrict__ r2,
                                                   ushort* __restrict__ WB1,
                                                   ushort* __restrict__ WB2,
                                                   ushort* __restrict__ RB1,
                                                   ushort* __restrict__ RB2,
                                                   uint4* __restrict__ zero_base) {
    int t = blockIdx.x * 256 + threadIdx.x;
    // zero cnt+used: 2*NSEG ints = 400000 uint4s
    for (int i = t; i < (2 * NSEG) / 4; i += 1152 * 256)
        zero_base[i] = make_uint4(0u, 0u, 0u, 0u);

    if (t < 262144) {                               // WB1 / WB2
        const float* W = (t < 131072) ? W1 : W2;
        ushort* WB     = (t < 131072) ? WB1 : WB2;
        int idx = t & 131071;
        int i  = idx & 7;
        int lm = (idx >> 3) & 15;
        int kg = (idx >> 7) & 3;
        int mt = (idx >> 9) & 1;
        int b  = (idx >> 10) & 3;
        int r  = idx >> 12;
        WB[idx] = f2bfbits(W[((size_t)(r * 4 + b) * 32 + kg * 8 + i) * 32 + mt * 16 + lm]);
    } else if (t < 294912) {                        // RB1 / RB2
        int u = t - 262144;
        const float* R = (u < 16384) ? r1 : r2;
        ushort* RB     = (u < 16384) ? RB1 : RB2;
        int idx = u & 16383;
        int i  = idx & 7;
        int lm = (idx >> 3) & 15;
        int kg = (idx >> 7) & 3;
        int kc = (idx >> 9) & 3;
        int mt = (idx >> 11) & 7;
        RB[idx] = f2bfbits(R[(size_t)(kc * 32 + kg * 8 + i) * DIM + mt * 16 + lm]);
    }
}

// ---------------------------------------------------------------------------
// CSR build: count (+used flag) -> joint scan {cnt,used} (block-local; bsum
// applied by consumers; used flag packed into cmap bit 31) -> scatter
// (merged into fused1 launch as TRAILING blocks -- round-14 champion).
// ---------------------------------------------------------------------------
__global__ __launch_bounds__(256) void count_kernel(const int* __restrict__ src,
                                                    const int* __restrict__ dst,
                                                    const int* __restrict__ et,
                                                    int* __restrict__ cnt,
                                                    int* __restrict__ used, int E) {
    int e = blockIdx.x * 256 + threadIdx.x;
    if (e < E) {
        int r = et[e];
        atomicAdd(&cnt[dst[e] * N_REL + r], 1);
        used[r * N_NODES + src[e]] = 1;        // benign race, all write 1
    }
}

// joint scan: cmap[idx] = (block-local excl prefix of used) | (used<<31)
__global__ __launch_bounds__(256) void scan1j_kernel(const int* __restrict__ cnt,
                                                     const int* __restrict__ used,
                                                     int* __restrict__ off,
                                                     int* __restrict__ cmap,
                                                     int2* __restrict__ bsum, int M) {
    const int t = threadIdx.x;
    const int base = blockIdx.x * SCAN_BLK + t * 4;
    int c[4], u[4];
#pragma unroll
    for (int i = 0; i < 4; ++i) {
        int idx = base + i;
        c[i] = (idx < M) ? cnt[idx] : 0;
        u[i] = (idx < M) ? used[idx] : 0;
    }
    int cs = c[0] + c[1] + c[2] + c[3];
    int us = u[0] + u[1] + u[2] + u[3];
    const int lane = t & 63, wid = t >> 6;
    int cinc = cs, uinc = us;
    for (int d = 1; d < 64; d <<= 1) {
        int a = __shfl_up(cinc, d, 64);
        int b = __shfl_up(uinc, d, 64);
        if (lane >= d) { cinc += a; uinc += b; }
    }
    __shared__ int cw[5], uw[5];
    if (lane == 63) { cw[wid] = cinc; uw[wid] = uinc; }
    __syncthreads();
    if (t == 0) {
        int a = 0, b = 0;
        for (int w = 0; w < 4; ++w) {
            int x = cw[w]; cw[w] = a; a += x;
            int y = uw[w]; uw[w] = b; b += y;
        }
        cw[4] = a; uw[4] = b;
    }
    __syncthreads();
    int cex = cinc - cs + cw[wid];
    int uex = uinc - us + uw[wid];
#pragma unroll
    for (int i = 0; i < 4; ++i) {
        int idx = base + i;
        if (idx < M) {
            off[idx] = cex;
            cmap[idx] = uex | (u[i] << 31);
        }
        cex += c[i]; uex += u[i];
    }
    if (t == 0) bsum[blockIdx.x] = make_int2(cw[4], uw[4]);
}

__global__ __launch_bounds__(1024) void scan2j_kernel(int2* __restrict__ bsum, int nb) {
    const int t = threadIdx.x;
    int2 s = (t < nb) ? bsum[t] : make_int2(0, 0);
    const int lane = t & 63, wid = t >> 6;
    int ci = s.x, ui = s.y;
    for (int d = 1; d < 64; d <<= 1) {
        int a = __shfl_up(ci, d, 64);
        int b = __shfl_up(ui, d, 64);
        if (lane >= d) { ci += a; ui += b; }
    }
    __shared__ int cw[16], uw[16];
    if (lane == 63) { cw[wid] = ci; uw[wid] = ui; }
    __syncthreads();
    if (t == 0) {
        int a = 0, b = 0;
        for (int w = 0; w < 16; ++w) {
            int x = cw[w]; cw[w] = a; a += x;
            int y = uw[w]; uw[w] = b; b += y;
        }
    }
    __syncthreads();
    if (t < nb) bsum[t] = make_int2(ci - s.x + cw[wid], ui - s.y + uw[wid]);
}

// slow-fallback scan (single array) + scatter (srcs list)
__global__ __launch_bounds__(256) void scan1_kernel(const int* __restrict__ in,
                                                    int* __restrict__ out,
                                                    int* __restrict__ bsum, int M) {
    const int t = threadIdx.x;
    const int base = blockIdx.x * SCAN_BLK + t * 4;
    int v0 = (base + 0 < M) ? in[base + 0] : 0;
    int v1 = (base + 1 < M) ? in[base + 1] : 0;
    int v2 = (base + 2 < M) ? in[base + 2] : 0;
    int v3 = (base + 3 < M) ? in[base + 3] : 0;
    const int s = v0 + v1 + v2 + v3;
    const int lane = t & 63, wid = t >> 6;
    int inc = s;
    for (int d = 1; d < 64; d <<= 1) {
        int u = __shfl_up(inc, d, 64);
        if (lane >= d) inc += u;
    }
    __shared__ int wsum[5];
    if (lane == 63) wsum[wid] = inc;
    __syncthreads();
    if (t == 0) {
        int a = 0;
        for (int w = 0; w < 4; ++w) { int u = wsum[w]; wsum[w] = a; a += u; }
        wsum[4] = a;
    }
    __syncthreads();
    const int ex = inc - s + wsum[wid];
    if (base + 0 < M) out[base + 0] = ex;
    if (base + 1 < M) out[base + 1] = ex + v0;
    if (base + 2 < M) out[base + 2] = ex + v0 + v1;
    if (base + 3 < M) out[base + 3] = ex + v0 + v1 + v2;
    if (t == 0) bsum[blockIdx.x] = wsum[4];
}

__global__ __launch_bounds__(1024) void scan2_kernel(int* __restrict__ bsum, int nb) {
    const int t = threadIdx.x;
    int s = (t < nb) ? bsum[t] : 0;
    const int lane = t & 63, wid = t >> 6;
    int inc = s;
    for (int d = 1; d < 64; d <<= 1) {
        int u = __shfl_up(inc, d, 64);
        if (lane >= d) inc += u;
    }
    __shared__ int wsum[16];
    if (lane == 63) wsum[wid] = inc;
    __syncthreads();
    if (t == 0) {
        int a = 0;
        for (int w = 0; w < 16; ++w) { int u = wsum[w]; wsum[w] = a; a += u; }
    }
    __syncthreads();
    const int ex = inc - s + wsum[wid];
    if (t < nb) bsum[t] = ex;
}

__global__ __launch_bounds__(256) void scan3_kernel(int* __restrict__ out,
                                                    const int* __restrict__ bsum, int M) {
    int i = blockIdx.x * 256 + threadIdx.x;
    if (i < M) out[i] += bsum[i / SCAN_BLK];
}

__global__ __launch_bounds__(256) void scatter_old_kernel(const int* __restrict__ src,
                                                          const int* __restrict__ dst,
                                                          const int* __restrict__ et,
                                                          int* __restrict__ off,
                                                          int* __restrict__ srcs, int E) {
    int e = blockIdx.x * 256 + threadIdx.x;
    if (e < E) {
        int seg = dst[e] * N_REL + et[e];
        int pos = atomicAdd(&off[seg], 1);
        srcs[pos] = src[e];
    }
}

// ---------------------------------------------------------------------------
// FUSED transform (+merged scatter as TRAILING blocks -- round-14 champion).
// Fused part: relation-split (8 rels per y-slice), tree rowmax, magic-
// rounding int8 quantize, compact table (flag+cid from ONE packed cmap read);
// dense root GEMM split across y (mt 0-3 / 4-7).
// ---------------------------------------------------------------------------
template<bool IN_BF16, bool OUT_BF16, bool RELU, bool WITH_SCATTER>
__global__ __launch_bounds__(256) void fused_kernel(const void* __restrict__ xin,
                                                    const ushort* __restrict__ WB,
                                                    const ushort* __restrict__ RB,
                                                    const float* __restrict__ bias,
                                                    const int* __restrict__ cmap,
                                                    const int2* __restrict__ bsum,
                                                    char* __restrict__ tab,
                                                    float* __restrict__ scl,
                                                    void* __restrict__ outv,
                                                    const int* __restrict__ src,
                                                    const int* __restrict__ dstv,
                                                    const int* __restrict__ et,
                                                    int* __restrict__ off,
                                                    const int* __restrict__ cnt,
                                                    int2* __restrict__ evec) {
    const int bid = blockIdx.x;
    if (WITH_SCATTER && bid >= 2 * NWTB) {
        // ---- scatter part (trailing blocks): 2 edges per thread ----
        const int e0 = (bid - 2 * NWTB) * 512 + threadIdx.x;
#pragma unroll
        for (int q = 0; q < 2; ++q) {
            const int e = e0 + q * 256;
            if (e < N_EDGES) {
                int r = et[e];
                int seg = dstv[e] * N_REL + r;
                int pos = atomicAdd(&off[seg], 1) + bsum[seg >> 10].x;
                float inv = 1.0f / (float)cnt[seg];
                int grow = r * N_NODES + src[e];
                int g = (cmap[grow] & 0x7FFFFFFF) + bsum[grow >> 10].y;
                evec[pos] = make_int2(g, __float_as_int(inv));
            }
        }
        return;
    }

    const int ybit = (bid >= NWTB) ? 1 : 0;
    const int xb   = bid - ybit * NWTB;
    const int wv = threadIdx.x >> 6;
    const int l  = threadIdx.x & 63;
    const int wt = xb * 4 + wv;
    if (wt >= NWT) return;
    const int lm = l & 15;
    const int kg = l >> 4;
    const int node = wt * 16 + lm;

    // x row fragments for all 4 K-blocks (shared by both parts)
    s8v bfr[4];
#pragma unroll
    for (int b = 0; b < 4; ++b) {
        if (IN_BF16) {
            const ushort* xp = (const ushort*)xin + (size_t)node * DIM + b * BS + kg * 8;
            u8v u = *(const u8v*)xp;
#pragma unroll
            for (int i = 0; i < 8; ++i) {
                unsigned short us = u[i];
                if (RELU) us = (us & 0x8000u) ? (unsigned short)0 : us;
                bfr[b][i] = (short)us;
            }
        } else {
            const float* xp = (const float*)xin + (size_t)node * DIM + b * BS + kg * 8;
#pragma unroll
            for (int i = 0; i < 8; ++i) {
                float v = xp[i];
                if (RELU) v = fmaxf(v, 0.f);
                bfr[b][i] = (short)f2bfbits(v);
            }
        }
    }

    // ---- part 1: int8 message table, 8 relations for this y ----
    const int rbase = ybit * 8;
    const float MAGIC = 12582912.0f;   // 1.5 * 2^23: low byte = int8(RNE(x))
#pragma unroll 2
    for (int ri = 0; ri < 8; ++ri) {
        const int rr = rbase + ri;
        const int grow = rr * N_NODES + node;
        const int cv   = cmap[grow];            // single packed load
        const bool flag = cv < 0;
        const int cid  = (cv & 0x7FFFFFFF) + bsum[grow >> 10].y;
        f4v acc[4][2];
#pragma unroll
        for (int b = 0; b < 4; ++b) {
#pragma unroll
            for (int mt = 0; mt < 2; ++mt) {
                s8v afrag = *(const s8v*)&WB[((((rr * 4 + b) * 2 + mt) * 4 + kg) * 16 + lm) * 8];
                f4v z = {0.f, 0.f, 0.f, 0.f};
                acc[b][mt] = __builtin_amdgcn_mfma_f32_16x16x32_bf16(afrag, bfr[b], z, 0, 0, 0);
            }
        }
        // rowmax: depth-5 tree over 32 in-lane values, then 2 shfl_xor
        float t8[8];
#pragma unroll
        for (int b = 0; b < 4; ++b)
#pragma unroll
            for (int mt = 0; mt < 2; ++mt)
                t8[b * 2 + mt] = fmaxf(fmaxf(fabsf(acc[b][mt][0]), fabsf(acc[b][mt][1])),
                                       fmaxf(fabsf(acc[b][mt][2]), fabsf(acc[b][mt][3])));
        float m = fmaxf(fmaxf(fmaxf(t8[0], t8[1]), fmaxf(t8[2], t8[3])),
                        fmaxf(fmaxf(t8[4], t8[5]), fmaxf(t8[6], t8[7])));
        m = fmaxf(m, __shfl_xor(m, 16, 64));
        m = fmaxf(m, __shfl_xor(m, 32, 64));
        m = fmaxf(m, 1e-30f);

        if (flag) {
            const float qs = 127.0f / m;
            unsigned int d[8];
#pragma unroll
            for (int b = 0; b < 4; ++b) {
#pragma unroll
                for (int mt = 0; mt < 2; ++mt) {
                    // magic rounding: fma then take byte0 (two's-complement int8)
                    unsigned f0 = __float_as_uint(fmaf(acc[b][mt][0], qs, MAGIC));
                    unsigned f1 = __float_as_uint(fmaf(acc[b][mt][1], qs, MAGIC));
                    unsigned f2 = __float_as_uint(fmaf(acc[b][mt][2], qs, MAGIC));
                    unsigned f3 = __float_as_uint(fmaf(acc[b][mt][3], qs, MAGIC));
                    unsigned t01 = __builtin_amdgcn_perm(f1, f0, 0x00000400u);
                    unsigned t23 = __builtin_amdgcn_perm(f3, f2, 0x00000400u);
                    d[b * 2 + mt] = __builtin_amdgcn_perm(t23, t01, 0x05040100u);
                }
            }
            char* gp = tab + (size_t)cid * 128 + kg * 32;
            *(uint4*)gp        = make_uint4(d[0], d[1], d[2], d[3]);
            *(uint4*)(gp + 16) = make_uint4(d[4], d[5], d[6], d[7]);
            if (kg == 0) scl[cid] = m * (1.0f / 127.0f);
        }
    }

    // ---- part 2: dense root GEMM + bias, mt range split across y ----
    {
        const int mt0 = ybit * 4;
#pragma unroll 2
        for (int mt = mt0; mt < mt0 + 4; ++mt) {
            const int col0 = mt * 16 + kg * 4;
            f4v acc = *(const f4v*)&bias[col0];
#pragma unroll
            for (int kc = 0; kc < 4; ++kc) {
                s8v afrag = *(const s8v*)&RB[(((mt * 4 + kc) * 4 + kg) * 16 + lm) * 8];
                acc = __builtin_amdgcn_mfma_f32_16x16x32_bf16(afrag, bfr[kc], acc, 0, 0, 0);
            }
            if (OUT_BF16) {
                unsigned int p0 = (unsigned int)f2bfbits(acc[0]) |
                                  ((unsigned int)f2bfbits(acc[1]) << 16);
                unsigned int p1 = (unsigned int)f2bfbits(acc[2]) |
                                  ((unsigned int)f2bfbits(acc[3]) << 16);
                *(uint2*)((ushort*)outv + (size_t)node * DIM + col0) = make_uint2(p0, p1);
            } else {
                *(f4v*)((float*)outv + (size_t)node * DIM + col0) = acc;
            }
        }
    }
}

// ---------------------------------------------------------------------------
// Edge-stream aggregate over compact int8 table. Half-wave per dst node;
// start/end from block-local off + bsum (off holds segment ENDs post-scatter).
// ---------------------------------------------------------------------------
template<bool OUT_BF16>
__global__ __launch_bounds__(256) void agg8_kernel(const int2* __restrict__ evec,
                                                   const int* __restrict__ off,
                                                   const int2* __restrict__ bsum,
                                                   const char* __restrict__ tab,
                                                   const float* __restrict__ scl,
                                                   void* __restrict__ outv) {
    const int hw = threadIdx.x >> 5;
    const int o  = threadIdx.x & 31;
    const int v  = blockIdx.x * 8 + hw;

    const int ei = v * N_REL + N_REL - 1;
    const int end = off[ei] + bsum[ei >> 10].x;
    int start = 0;
    if (v > 0) {
        const int si = v * N_REL - 1;
        start = off[si] + bsum[si >> 10].x;
    }

    const int p = o >> 4;            // edge parity within the quad (0/1)
    const int w = o & 15;            // 8-byte sub-chunk of the 128B row

    float acc[8];
#pragma unroll
    for (int j = 0; j < 8; ++j) acc[j] = 0.f;

#pragma unroll 2
    for (int base = start; base < end; base += 4) {
        const int k0 = base + p;
        const int k1 = base + 2 + p;
        const int2 e0 = evec[min(k0, end - 1)];
        const int2 e1 = evec[min(k1, end - 1)];
        const int g0 = e0.x, g1 = e1.x;
        const float i0 = (k0 < end) ? __int_as_float(e0.y) : 0.f;
        const float i1 = (k1 < end) ? __int_as_float(e1.y) : 0.f;
        const uint2 q0 = *(const uint2*)(tab + (size_t)g0 * 128 + w * 8);
        const uint2 q1 = *(const uint2*)(tab + (size_t)g1 * 128 + w * 8);
        const float s0 = scl[g0] * i0;
        const float s1 = scl[g1] * i1;
#pragma unroll
        for (int j = 0; j < 4; ++j) {
            acc[j]     = fmaf((float)(int)(signed char)(q0.x >> (8 * j)), s0, acc[j]);
            acc[4 + j] = fmaf((float)(int)(signed char)(q0.y >> (8 * j)), s0, acc[4 + j]);
        }
#pragma unroll
        for (int j = 0; j < 4; ++j) {
            acc[j]     = fmaf((float)(int)(signed char)(q1.x >> (8 * j)), s1, acc[j]);
            acc[4 + j] = fmaf((float)(int)(signed char)(q1.y >> (8 * j)), s1, acc[4 + j]);
        }
    }
#pragma unroll
    for (int j = 0; j < 8; ++j)
        acc[j] += __shfl_xor(acc[j], 16, 32);

    if (o < 16) {
        const int base0 = (o & 3) * 32 + (o >> 2) * 4;     // dim of acc[0]
        if (OUT_BF16) {
            ushort* hp = (ushort*)outv + (size_t)v * DIM + base0;
            ushort4 a0 = *(ushort4*)hp;
            ushort4 a1 = *(ushort4*)(hp + 16);
            a0.x = f2bfbits(bf2f(a0.x) + acc[0]);
            a0.y = f2bfbits(bf2f(a0.y) + acc[1]);
            a0.z = f2bfbits(bf2f(a0.z) + acc[2]);
            a0.w = f2bfbits(bf2f(a0.w) + acc[3]);
            a1.x = f2bfbits(bf2f(a1.x) + acc[4]);
            a1.y = f2bfbits(bf2f(a1.y) + acc[5]);
            a1.z = f2bfbits(bf2f(a1.z) + acc[6]);
            a1.w = f2bfbits(bf2f(a1.w) + acc[7]);
            *(ushort4*)hp        = a0;
            *(ushort4*)(hp + 16) = a1;
        } else {
            float* op = (float*)outv + (size_t)v * DIM + base0;
            float4 r0 = *(float4*)op;
            float4 r1 = *(float4*)(op + 16);
            r0.x += acc[0]; r0.y += acc[1]; r0.z += acc[2]; r0.w += acc[3];
            r1.x += acc[4]; r1.y += acc[5]; r1.z += acc[6]; r1.w += acc[7];
            *(float4*)op        = r0;
            *(float4*)(op + 16) = r1;
        }
    }
}

// ---------------------------------------------------------------------------
// Slow fallback (tiny ws): fp32 dense + gather-aggregate on x directly.
// ---------------------------------------------------------------------------
__global__ __launch_bounds__(256) void count_fb_kernel(const int* __restrict__ dst,
                                                       const int* __restrict__ et,
                                                       int* __restrict__ cnt, int E) {
    int e = blockIdx.x * 256 + threadIdx.x;
    if (e < E) atomicAdd(&cnt[dst[e] * N_REL + et[e]], 1);
}

template<bool RELU>
__global__ __launch_bounds__(256) void dense_old_kernel(const float* __restrict__ x,
                                                        const float* __restrict__ root,
                                                        const float* __restrict__ bias,
                                                        float* __restrict__ out) {
    const int wv = threadIdx.x >> 6;
    const int l  = threadIdx.x & 63;
    const int wt = blockIdx.x * 4 + wv;
    if (wt >= NWT) return;
    const int nbase = wt * 16;
    const int lm = l & 15;
    const int kg = l >> 4;
    const int node = nbase + lm;

    s8v bfr[4];
#pragma unroll
    for (int kc = 0; kc < 4; ++kc) {
        const float* xp = &x[(size_t)node * DIM + kc * BS + kg * 8];
#pragma unroll
        for (int i = 0; i < 8; ++i) {
            float v = xp[i];
            if (RELU) v = fmaxf(v, 0.f);
            bfr[kc][i] = (short)f2bfbits(v);
        }
    }
#pragma unroll 2
    for (int mt = 0; mt < 8; ++mt) {
        const int col0 = mt * 16 + kg * 4;
        f4v acc = *(const f4v*)&bias[col0];
#pragma unroll
        for (int kc = 0; kc < 4; ++kc) {
            const float* rp = &root[(size_t)(kc * BS + kg * 8) * DIM + mt * 16 + lm];
            s8v afrag;
#pragma unroll
            for (int i = 0; i < 8; ++i)
                afrag[i] = (short)f2bfbits(rp[i * DIM]);
            acc = __builtin_amdgcn_mfma_f32_16x16x32_bf16(afrag, bfr[kc], acc, 0, 0, 0);
        }
        *(f4v*)&out[(size_t)node * DIM + col0] = acc;
    }
}

template<bool RELU>
__global__ __launch_bounds__(256) void agg_fallback_kernel(const int* __restrict__ srcs,
                                                           const int* __restrict__ off,
                                                           const int* __restrict__ cnt,
                                                           const float* __restrict__ x,
                                                           const float* __restrict__ W,
                                                           float* __restrict__ out) {
    __shared__ float Wsh[N_REL * BS * BS];
    const int bblk = blockIdx.y;
    for (int idx = threadIdx.x * 4; idx < N_REL * BS * BS; idx += 1024) {
        int r = idx >> 10, rest = idx & 1023;
        *(float4*)&Wsh[idx] = *(const float4*)&W[(r * NBLK + bblk) * 1024 + rest];
    }
    __syncthreads();
    const int hw = threadIdx.x >> 5;
    const int o  = threadIdx.x & 31;
    const int v  = blockIdx.x * 8 + hw;
    int endv = 0, cv = 0;
    if (o < N_REL) { endv = off[v * N_REL + o]; cv = cnt[v * N_REL + o]; }
    float acc = out[v * DIM + bblk * BS + o];
    for (int r = 0; r < N_REL; ++r) {
        const int c = __shfl(cv, r, 32);
        if (c == 0) continue;
        const int end = __shfl(endv, r, 32);
        float xs = 0.f;
        for (int k = end - c; k < end; ++k) {
            const int s = srcs[k];
            float xv = x[s * DIM + bblk * BS + o];
            if (RELU) xv = fmaxf(xv, 0.f);
            xs += xv;
        }
        xs *= (1.0f / (float)c);
        const float* wr = &Wsh[r * (BS * BS)];
#pragma unroll
        for (int i = 0; i < BS; i += 2) {
            float xi0 = __shfl(xs, i, 32);
            float xi1 = __shfl(xs, i + 1, 32);
            acc = fmaf(xi0, wr[i * BS + o], acc);
            acc = fmaf(xi1, wr[(i + 1) * BS + o], acc);
        }
    }
    out[v * DIM + bblk * BS + o] = acc;
}

// ---------------------------------------------------------------------------
extern "C" void kernel_launch(void* const* d_in, const int* in_sizes, int n_in,
                              void* d_out, int out_size, void* d_ws, size_t ws_size,
                              hipStream_t stream) {
    const int*   edge_index = (const int*)d_in[0];
    const int*   src   = edge_index;
    const int*   dstv  = edge_index + N_EDGES;
    const int*   et    = (const int*)d_in[1];
    const float* x0    = (const float*)d_in[2];
    const float* W1    = (const float*)d_in[3];
    const float* root1 = (const float*)d_in[4];
    const float* bias1 = (const float*)d_in[5];
    const float* W2    = (const float*)d_in[6];
    const float* root2 = (const float*)d_in[7];
    const float* bias2 = (const float*)d_in[8];
    float* out = (float*)d_out;

    // ---- fast-path workspace layout (138.2 MB total; round-14 proven) ----
    char* ws = (char*)d_ws;
    ushort* h    = (ushort*)ws;                             // 12,800,000 (bf16)
    int*    cnt  = (int*)   (ws + 12800000);                //  3,200,000
    int*    used = (int*)   (ws + 16000000);                //  3,200,000 (adj to cnt)
    int*    off  = (int*)   (ws + 19200000);                //  3,200,000
    int*    cmap = (int*)   (ws + 22400000);                //  3,200,000
    int2*   evec = (int2*)  (ws + 25600000);                //  6,400,000
    int2*   bsum = (int2*)  (ws + 32000000);                //      8,192
    ushort* WB1  = (ushort*)(ws + 32008192);                //    262,144
    ushort* WB2  = (ushort*)(ws + 32270336);                //    262,144
    ushort* RB1  = (ushort*)(ws + 32532480);                //     32,768
    ushort* RB2  = (ushort*)(ws + 32565248);                //     32,768
    float*  scl  = (float*) (ws + 32598016);                //  3,200,000
    char*   tab  =          (ws + 35798016);                // 102,400,000
    const size_t FAST_NEED = 138198016ull;

    const int egrid = (N_EDGES + 255) / 256;     // 3125

    if (ws_size >= FAST_NEED) {
        prep_kernel<<<1152, 256, 0, stream>>>(W1, W2, root1, root2, WB1, WB2,
                                              RB1, RB2, (uint4*)cnt);
        count_kernel<<<egrid, 256, 0, stream>>>(src, dstv, et, cnt, used, N_EDGES);
        scan1j_kernel<<<N_SCAN_BLKS, 256, 0, stream>>>(cnt, used, off, cmap, bsum, NSEG);
        scan2j_kernel<<<1, 1024, 0, stream>>>(bsum, N_SCAN_BLKS);

        const int ngrid = N_NODES / 8;           // 6250

        // ---- layer 1: fused transform+dense + trailing SCATTER blocks ----
        fused_kernel<false, true, false, true><<<2 * NWTB + SCATB, 256, 0, stream>>>(
            x0, WB1, RB1, bias1, cmap, bsum, tab, scl, h,
            src, dstv, et, off, cnt, evec);
        agg8_kernel<true><<<ngrid, 256, 0, stream>>>(evec, off, bsum, tab, scl, h);

        // ---- layer 2: fused transform+dense ----
        fused_kernel<true, false, true, false><<<2 * NWTB, 256, 0, stream>>>(
            h, WB2, RB2, bias2, cmap, bsum, tab, scl, out,
            src, dstv, et, off, cnt, evec);
        agg8_kernel<false><<<ngrid, 256, 0, stream>>>(evec, off, bsum, tab, scl, out);
    } else {
        // ---- slow fallback (ws >= 35.3 MB): fp32 h + direct gather-agg ----
        float* hf    = (float*)d_ws;
        int*   cntf  = (int*)((char*)d_ws + 25600000);
        int*   offf  = (int*)((char*)d_ws + 28800000);
        int*   srcsf = (int*)((char*)d_ws + 32000000);
        int*   bsumf = (int*)((char*)d_ws + 35200000);

        hipMemsetAsync(cntf, 0, (size_t)NSEG * sizeof(int), stream);
        count_fb_kernel<<<egrid, 256, 0, stream>>>(dstv, et, cntf, N_EDGES);
        scan1_kernel<<<N_SCAN_BLKS, 256, 0, stream>>>(cntf, offf, bsumf, NSEG);
        scan2_kernel<<<1, 1024, 0, stream>>>(bsumf, N_SCAN_BLKS);
        scan3_kernel<<<(NSEG + 255) / 256, 256, 0, stream>>>(offf, bsumf, NSEG);
        scatter_old_kernel<<<egrid, 256, 0, stream>>>(src, dstv, et, offf, srcsf, N_EDGES);

        dim3 fgrid2(N_NODES / 8, NBLK);
        dense_old_kernel<false><<<NWTB, 256, 0, stream>>>(x0, root1, bias1, hf);
        agg_fallback_kernel<false><<<fgrid2, 256, 0, stream>>>(srcsf, offf, cntf, x0, W1, hf);
        dense_old_kernel<true><<<NWTB, 256, 0, stream>>>(hf, root2, bias2, out);
        agg_fallback_kernel<true><<<fgrid2, 256, 0, stream>>>(srcsf, offf, cntf, hf, W2, out);
    }
}

// Round 19
// 227.836 us; speedup vs baseline: 1.1076x; 1.0085x over previous
//
#include <hip/hip_runtime.h>
#include <hip/hip_bf16.h>

#define N_NODES 50000
#define N_REL   16
#define DIM     128
#define NBLK    4
#define BS      32
#define N_EDGES 800000
#define NSEG    (N_NODES * N_REL)
#define SCAN_BLK 1024
#define N_SCAN_BLKS ((NSEG + SCAN_BLK - 1) / SCAN_BLK)
#define NWT     (N_NODES / 16)        // 3125 wave-tiles of 16 nodes
#define NWTB    ((NWT + 3) / 4)       // 782 fused blocks per y-slice
#define SCATB   ((N_EDGES + 511) / 512)  // 1563 scatter blocks (2 edges/thread)

typedef __attribute__((ext_vector_type(8))) short s8v;            // 8 bf16
typedef __attribute__((ext_vector_type(8))) unsigned short u8v;   // 8 bf16 bits
typedef __attribute__((ext_vector_type(4))) float f4v;            // mfma C/D

__device__ __forceinline__ float bf2f(unsigned short u) {
    return __uint_as_float(((unsigned int)u) << 16);
}
__device__ __forceinline__ unsigned short f2bfbits(float f) {   // RNE
    unsigned int u = __float_as_uint(f);
    return (unsigned short)((u + 0x7fffu + ((u >> 16) & 1u)) >> 16);
}

// ---------------------------------------------------------------------------
// Prep (+zero cnt/used): convert W/root to bf16 A-fragment lane order and
// grid-stride zero the 6.4MB cnt+used region.
// ---------------------------------------------------------------------------
__global__ __launch_bounds__(256) void prep_kernel(const float* __restrict__ W1,
                                                   const float* __restrict__ W2,
                                                   const float* __restrict__ r1,
                                                   const float* __restrict__ r2,
                                                   ushort* __restrict__ WB1,
                                                   ushort* __restrict__ WB2,
                                                   ushort* __restrict__ RB1,
                                                   ushort* __restrict__ RB2,
                                                   uint4* __restrict__ zero_base) {
    int t = blockIdx.x * 256 + threadIdx.x;
    for (int i = t; i < (2 * NSEG) / 4; i += 1152 * 256)
        zero_base[i] = make_uint4(0u, 0u, 0u, 0u);

    if (t < 262144) {                               // WB1 / WB2
        const float* W = (t < 131072) ? W1 : W2;
        ushort* WB     = (t < 131072) ? WB1 : WB2;
        int idx = t & 131071;
        int i  = idx & 7;
        int lm = (idx >> 3) & 15;
        int kg = (idx >> 7) & 3;
        int mt = (idx >> 9) & 1;
        int b  = (idx >> 10) & 3;
        int r  = idx >> 12;
        WB[idx] = f2bfbits(W[((size_t)(r * 4 + b) * 32 + kg * 8 + i) * 32 + mt * 16 + lm]);
    } else if (t < 294912) {                        // RB1 / RB2
        int u = t - 262144;
        const float* R = (u < 16384) ? r1 : r2;
        ushort* RB     = (u < 16384) ? RB1 : RB2;
        int idx = u & 16383;
        int i  = idx & 7;
        int lm = (idx >> 3) & 15;
        int kg = (idx >> 7) & 3;
        int kc = (idx >> 9) & 3;
        int mt = (idx >> 11) & 7;
        RB[idx] = f2bfbits(R[(size_t)(kc * 32 + kg * 8 + i) * DIM + mt * 16 + lm]);
    }
}

// ---------------------------------------------------------------------------
// CSR build: count (+used flag) -> joint scan {cnt,used} (block-local; bsum
// applied by consumers; used flag packed into cmap bit 31) -> scatter
// (merged into fused1 launch as TRAILING blocks -- champion placement).
// ---------------------------------------------------------------------------
__global__ __launch_bounds__(256) void count_kernel(const int* __restrict__ src,
                                                    const int* __restrict__ dst,
                                                    const int* __restrict__ et,
                                                    int* __restrict__ cnt,
                                                    int* __restrict__ used, int E) {
    int e = blockIdx.x * 256 + threadIdx.x;
    if (e < E) {
        int r = et[e];
        atomicAdd(&cnt[dst[e] * N_REL + r], 1);
        used[r * N_NODES + src[e]] = 1;        // benign race, all write 1
    }
}

// joint scan: cmap[idx] = (block-local excl prefix of used) | (used<<31)
__global__ __launch_bounds__(256) void scan1j_kernel(const int* __restrict__ cnt,
                                                     const int* __restrict__ used,
                                                     int* __restrict__ off,
                                                     int* __restrict__ cmap,
                                                     int2* __restrict__ bsum, int M) {
    const int t = threadIdx.x;
    const int base = blockIdx.x * SCAN_BLK + t * 4;
    int c[4], u[4];
#pragma unroll
    for (int i = 0; i < 4; ++i) {
        int idx = base + i;
        c[i] = (idx < M) ? cnt[idx] : 0;
        u[i] = (idx < M) ? used[idx] : 0;
    }
    int cs = c[0] + c[1] + c[2] + c[3];
    int us = u[0] + u[1] + u[2] + u[3];
    const int lane = t & 63, wid = t >> 6;
    int cinc = cs, uinc = us;
    for (int d = 1; d < 64; d <<= 1) {
        int a = __shfl_up(cinc, d, 64);
        int b = __shfl_up(uinc, d, 64);
        if (lane >= d) { cinc += a; uinc += b; }
    }
    __shared__ int cw[5], uw[5];
    if (lane == 63) { cw[wid] = cinc; uw[wid] = uinc; }
    __syncthreads();
    if (t == 0) {
        int a = 0, b = 0;
        for (int w = 0; w < 4; ++w) {
            int x = cw[w]; cw[w] = a; a += x;
            int y = uw[w]; uw[w] = b; b += y;
        }
        cw[4] = a; uw[4] = b;
    }
    __syncthreads();
    int cex = cinc - cs + cw[wid];
    int uex = uinc - us + uw[wid];
#pragma unroll
    for (int i = 0; i < 4; ++i) {
        int idx = base + i;
        if (idx < M) {
            off[idx] = cex;
            cmap[idx] = uex | (u[i] << 31);
        }
        cex += c[i]; uex += u[i];
    }
    if (t == 0) bsum[blockIdx.x] = make_int2(cw[4], uw[4]);
}

__global__ __launch_bounds__(1024) void scan2j_kernel(int2* __restrict__ bsum, int nb) {
    const int t = threadIdx.x;
    int2 s = (t < nb) ? bsum[t] : make_int2(0, 0);
    const int lane = t & 63, wid = t >> 6;
    int ci = s.x, ui = s.y;
    for (int d = 1; d < 64; d <<= 1) {
        int a = __shfl_up(ci, d, 64);
        int b = __shfl_up(ui, d, 64);
        if (lane >= d) { ci += a; ui += b; }
    }
    __shared__ int cw[16], uw[16];
    if (lane == 63) { cw[wid] = ci; uw[wid] = ui; }
    __syncthreads();
    if (t == 0) {
        int a = 0, b = 0;
        for (int w = 0; w < 16; ++w) {
            int x = cw[w]; cw[w] = a; a += x;
            int y = uw[w]; uw[w] = b; b += y;
        }
    }
    __syncthreads();
    if (t < nb) bsum[t] = make_int2(ci - s.x + cw[wid], ui - s.y + uw[wid]);
}

// slow-fallback scan (single array) + scatter (srcs list)
__global__ __launch_bounds__(256) void scan1_kernel(const int* __restrict__ in,
                                                    int* __restrict__ out,
                                                    int* __restrict__ bsum, int M) {
    const int t = threadIdx.x;
    const int base = blockIdx.x * SCAN_BLK + t * 4;
    int v0 = (base + 0 < M) ? in[base + 0] : 0;
    int v1 = (base + 1 < M) ? in[base + 1] : 0;
    int v2 = (base + 2 < M) ? in[base + 2] : 0;
    int v3 = (base + 3 < M) ? in[base + 3] : 0;
    const int s = v0 + v1 + v2 + v3;
    const int lane = t & 63, wid = t >> 6;
    int inc = s;
    for (int d = 1; d < 64; d <<= 1) {
        int u = __shfl_up(inc, d, 64);
        if (lane >= d) inc += u;
    }
    __shared__ int wsum[5];
    if (lane == 63) wsum[wid] = inc;
    __syncthreads();
    if (t == 0) {
        int a = 0;
        for (int w = 0; w < 4; ++w) { int u = wsum[w]; wsum[w] = a; a += u; }
        wsum[4] = a;
    }
    __syncthreads();
    const int ex = inc - s + wsum[wid];
    if (base + 0 < M) out[base + 0] = ex;
    if (base + 1 < M) out[base + 1] = ex + v0;
    if (base + 2 < M) out[base + 2] = ex + v0 + v1;
    if (base + 3 < M) out[base + 3] = ex + v0 + v1 + v2;
    if (t == 0) bsum[blockIdx.x] = wsum[4];
}

__global__ __launch_bounds__(1024) void scan2_kernel(int* __restrict__ bsum, int nb) {
    const int t = threadIdx.x;
    int s = (t < nb) ? bsum[t] : 0;
    const int lane = t & 63, wid = t >> 6;
    int inc = s;
    for (int d = 1; d < 64; d <<= 1) {
        int u = __shfl_up(inc, d, 64);
        if (lane >= d) inc += u;
    }
    __shared__ int wsum[16];
    if (lane == 63) wsum[wid] = inc;
    __syncthreads();
    if (t == 0) {
        int a = 0;
        for (int w = 0; w < 16; ++w) { int u = wsum[w]; wsum[w] = a; a += u; }
    }
    __syncthreads();
    const int ex = inc - s + wsum[wid];
    if (t < nb) bsum[t] = ex;
}

__global__ __launch_bounds__(256) void scan3_kernel(int* __restrict__ out,
                                                    const int* __restrict__ bsum, int M) {
    int i = blockIdx.x * 256 + threadIdx.x;
    if (i < M) out[i] += bsum[i / SCAN_BLK];
}

__global__ __launch_bounds__(256) void scatter_old_kernel(const int* __restrict__ src,
                                                          const int* __restrict__ dst,
                                                          const int* __restrict__ et,
                                                          int* __restrict__ off,
                                                          int* __restrict__ srcs, int E) {
    int e = blockIdx.x * 256 + threadIdx.x;
    if (e < E) {
        int seg = dst[e] * N_REL + et[e];
        int pos = atomicAdd(&off[seg], 1);
        srcs[pos] = src[e];
    }
}

// ---------------------------------------------------------------------------
// FUSED transform (+merged scatter as TRAILING blocks). Tab byte layout is
// FULL-LINE-PER-STORE: 128B row = [line0: lane kg at kg*16 holds d[0..3]]
// [line1: lane kg at 64+kg*16 holds d[4..7]] -- each uint4 store instruction
// covers complete 64B lines across the wave => no write-allocate RFO.
// ---------------------------------------------------------------------------
template<bool IN_BF16, bool OUT_BF16, bool RELU, bool WITH_SCATTER>
__global__ __launch_bounds__(256) void fused_kernel(const void* __restrict__ xin,
                                                    const ushort* __restrict__ WB,
                                                    const ushort* __restrict__ RB,
                                                    const float* __restrict__ bias,
                                                    const int* __restrict__ cmap,
                                                    const int2* __restrict__ bsum,
                                                    char* __restrict__ tab,
                                                    float* __restrict__ scl,
                                                    void* __restrict__ outv,
                                                    const int* __restrict__ src,
                                                    const int* __restrict__ dstv,
                                                    const int* __restrict__ et,
                                                    int* __restrict__ off,
                                                    const int* __restrict__ cnt,
                                                    int2* __restrict__ evec) {
    const int bid = blockIdx.x;
    if (WITH_SCATTER && bid >= 2 * NWTB) {
        // ---- scatter part (trailing blocks): 2 edges per thread ----
        const int e0 = (bid - 2 * NWTB) * 512 + threadIdx.x;
#pragma unroll
        for (int q = 0; q < 2; ++q) {
            const int e = e0 + q * 256;
            if (e < N_EDGES) {
                int r = et[e];
                int seg = dstv[e] * N_REL + r;
                int pos = atomicAdd(&off[seg], 1) + bsum[seg >> 10].x;
                float inv = 1.0f / (float)cnt[seg];
                int grow = r * N_NODES + src[e];
                int g = (cmap[grow] & 0x7FFFFFFF) + bsum[grow >> 10].y;
                evec[pos] = make_int2(g, __float_as_int(inv));
            }
        }
        return;
    }

    const int ybit = (bid >= NWTB) ? 1 : 0;
    const int xb   = bid - ybit * NWTB;
    const int wv = threadIdx.x >> 6;
    const int l  = threadIdx.x & 63;
    const int wt = xb * 4 + wv;
    if (wt >= NWT) return;
    const int lm = l & 15;
    const int kg = l >> 4;
    const int node = wt * 16 + lm;

    // x row fragments for all 4 K-blocks (shared by both parts)
    s8v bfr[4];
#pragma unroll
    for (int b = 0; b < 4; ++b) {
        if (IN_BF16) {
            const ushort* xp = (const ushort*)xin + (size_t)node * DIM + b * BS + kg * 8;
            u8v u = *(const u8v*)xp;
#pragma unroll
            for (int i = 0; i < 8; ++i) {
                unsigned short us = u[i];
                if (RELU) us = (us & 0x8000u) ? (unsigned short)0 : us;
                bfr[b][i] = (short)us;
            }
        } else {
            const float* xp = (const float*)xin + (size_t)node * DIM + b * BS + kg * 8;
#pragma unroll
            for (int i = 0; i < 8; ++i) {
                float v = xp[i];
                if (RELU) v = fmaxf(v, 0.f);
                bfr[b][i] = (short)f2bfbits(v);
            }
        }
    }

    // ---- part 1: int8 message table, 8 relations for this y ----
    const int rbase = ybit * 8;
    const float MAGIC = 12582912.0f;   // 1.5 * 2^23: low byte = int8(RNE(x))
#pragma unroll 2
    for (int ri = 0; ri < 8; ++ri) {
        const int rr = rbase + ri;
        const int grow = rr * N_NODES + node;
        const int cv   = cmap[grow];            // single packed load
        const bool flag = cv < 0;
        const int cid  = (cv & 0x7FFFFFFF) + bsum[grow >> 10].y;
        f4v acc[4][2];
#pragma unroll
        for (int b = 0; b < 4; ++b) {
#pragma unroll
            for (int mt = 0; mt < 2; ++mt) {
                s8v afrag = *(const s8v*)&WB[((((rr * 4 + b) * 2 + mt) * 4 + kg) * 16 + lm) * 8];
                f4v z = {0.f, 0.f, 0.f, 0.f};
                acc[b][mt] = __builtin_amdgcn_mfma_f32_16x16x32_bf16(afrag, bfr[b], z, 0, 0, 0);
            }
        }
        // rowmax: depth-5 tree over 32 in-lane values, then 2 shfl_xor
        float t8[8];
#pragma unroll
        for (int b = 0; b < 4; ++b)
#pragma unroll
            for (int mt = 0; mt < 2; ++mt)
                t8[b * 2 + mt] = fmaxf(fmaxf(fabsf(acc[b][mt][0]), fabsf(acc[b][mt][1])),
                                       fmaxf(fabsf(acc[b][mt][2]), fabsf(acc[b][mt][3])));
        float m = fmaxf(fmaxf(fmaxf(t8[0], t8[1]), fmaxf(t8[2], t8[3])),
                        fmaxf(fmaxf(t8[4], t8[5]), fmaxf(t8[6], t8[7])));
        m = fmaxf(m, __shfl_xor(m, 16, 64));
        m = fmaxf(m, __shfl_xor(m, 32, 64));
        m = fmaxf(m, 1e-30f);

        if (flag) {
            const float qs = 127.0f / m;
            unsigned int d[8];
#pragma unroll
            for (int b = 0; b < 4; ++b) {
#pragma unroll
                for (int mt = 0; mt < 2; ++mt) {
                    unsigned f0 = __float_as_uint(fmaf(acc[b][mt][0], qs, MAGIC));
                    unsigned f1 = __float_as_uint(fmaf(acc[b][mt][1], qs, MAGIC));
                    unsigned f2 = __float_as_uint(fmaf(acc[b][mt][2], qs, MAGIC));
                    unsigned f3 = __float_as_uint(fmaf(acc[b][mt][3], qs, MAGIC));
                    unsigned t01 = __builtin_amdgcn_perm(f1, f0, 0x00000400u);
                    unsigned t23 = __builtin_amdgcn_perm(f3, f2, 0x00000400u);
                    d[b * 2 + mt] = __builtin_amdgcn_perm(t23, t01, 0x05040100u);
                }
            }
            // full-line stores: store1 covers bytes [0,64) of the row,
            // store2 covers [64,128) -- no partial-line RFO.
            char* gp = tab + (size_t)cid * 128 + kg * 16;
            *(uint4*)gp        = make_uint4(d[0], d[1], d[2], d[3]);
            *(uint4*)(gp + 64) = make_uint4(d[4], d[5], d[6], d[7]);
            if (kg == 0) scl[cid] = m * (1.0f / 127.0f);
        }
    }

    // ---- part 2: dense root GEMM + bias, mt range split across y ----
    {
        const int mt0 = ybit * 4;
#pragma unroll 2
        for (int mt = mt0; mt < mt0 + 4; ++mt) {
            const int col0 = mt * 16 + kg * 4;
            f4v acc = *(const f4v*)&bias[col0];
#pragma unroll
            for (int kc = 0; kc < 4; ++kc) {
                s8v afrag = *(const s8v*)&RB[(((mt * 4 + kc) * 4 + kg) * 16 + lm) * 8];
                acc = __builtin_amdgcn_mfma_f32_16x16x32_bf16(afrag, bfr[kc], acc, 0, 0, 0);
            }
            if (OUT_BF16) {
                unsigned int p0 = (unsigned int)f2bfbits(acc[0]) |
                                  ((unsigned int)f2bfbits(acc[1]) << 16);
                unsigned int p1 = (unsigned int)f2bfbits(acc[2]) |
                                  ((unsigned int)f2bfbits(acc[3]) << 16);
                *(uint2*)((ushort*)outv + (size_t)node * DIM + col0) = make_uint2(p0, p1);
            } else {
                *(f4v*)((float*)outv + (size_t)node * DIM + col0) = acc;
            }
        }
    }
}

// ---------------------------------------------------------------------------
// Edge-stream aggregate over compact int8 table. Half-wave per dst node.
// New byte->dim decode for the full-line tab layout: lane w reads bytes
// [w*8, w*8+8): b = (w>>3)*2 + (w&1), kg = (w>>1)&3; dword0 -> dims
// b*32+kg*4+j (mt=0), dword1 -> +16 (mt=1).
// ---------------------------------------------------------------------------
template<bool OUT_BF16>
__global__ __launch_bounds__(256) void agg8_kernel(const int2* __restrict__ evec,
                                                   const int* __restrict__ off,
                                                   const int2* __restrict__ bsum,
                                                   const char* __restrict__ tab,
                                                   const float* __restrict__ scl,
                                                   void* __restrict__ outv) {
    const int hw = threadIdx.x >> 5;
    const int o  = threadIdx.x & 31;
    const int v  = blockIdx.x * 8 + hw;

    const int ei = v * N_REL + N_REL - 1;
    const int end = off[ei] + bsum[ei >> 10].x;
    int start = 0;
    if (v > 0) {
        const int si = v * N_REL - 1;
        start = off[si] + bsum[si >> 10].x;
    }

    const int p = o >> 4;            // edge parity within the quad (0/1)
    const int w = o & 15;            // 8-byte sub-chunk of the 128B row

    float acc[8];
#pragma unroll
    for (int j = 0; j < 8; ++j) acc[j] = 0.f;

#pragma unroll 2
    for (int base = start; base < end; base += 4) {
        const int k0 = base + p;
        const int k1 = base + 2 + p;
        const int2 e0 = evec[min(k0, end - 1)];
        const int2 e1 = evec[min(k1, end - 1)];
        const int g0 = e0.x, g1 = e1.x;
        const float i0 = (k0 < end) ? __int_as_float(e0.y) : 0.f;
        const float i1 = (k1 < end) ? __int_as_float(e1.y) : 0.f;
        const uint2 q0 = *(const uint2*)(tab + (size_t)g0 * 128 + w * 8);
        const uint2 q1 = *(const uint2*)(tab + (size_t)g1 * 128 + w * 8);
        const float s0 = scl[g0] * i0;
        const float s1 = scl[g1] * i1;
#pragma unroll
        for (int j = 0; j < 4; ++j) {
            acc[j]     = fmaf((float)(int)(signed char)(q0.x >> (8 * j)), s0, acc[j]);
            acc[4 + j] = fmaf((float)(int)(signed char)(q0.y >> (8 * j)), s0, acc[4 + j]);
        }
#pragma unroll
        for (int j = 0; j < 4; ++j) {
            acc[j]     = fmaf((float)(int)(signed char)(q1.x >> (8 * j)), s1, acc[j]);
            acc[4 + j] = fmaf((float)(int)(signed char)(q1.y >> (8 * j)), s1, acc[4 + j]);
        }
    }
#pragma unroll
    for (int j = 0; j < 8; ++j)
        acc[j] += __shfl_xor(acc[j], 16, 32);

    if (o < 16) {
        // decode: b = (o>>3)*2 + (o&1), kg = (o>>1)&3
        const int base0 = ((o >> 3) * 2 + (o & 1)) * 32 + ((o >> 1) & 3) * 4;
        if (OUT_BF16) {
            ushort* hp = (ushort*)outv + (size_t)v * DIM + base0;
            ushort4 a0 = *(ushort4*)hp;
            ushort4 a1 = *(ushort4*)(hp + 16);
            a0.x = f2bfbits(bf2f(a0.x) + acc[0]);
            a0.y = f2bfbits(bf2f(a0.y) + acc[1]);
            a0.z = f2bfbits(bf2f(a0.z) + acc[2]);
            a0.w = f2bfbits(bf2f(a0.w) + acc[3]);
            a1.x = f2bfbits(bf2f(a1.x) + acc[4]);
            a1.y = f2bfbits(bf2f(a1.y) + acc[5]);
            a1.z = f2bfbits(bf2f(a1.z) + acc[6]);
            a1.w = f2bfbits(bf2f(a1.w) + acc[7]);
            *(ushort4*)hp        = a0;
            *(ushort4*)(hp + 16) = a1;
        } else {
            float* op = (float*)outv + (size_t)v * DIM + base0;
            float4 r0 = *(float4*)op;
            float4 r1 = *(float4*)(op + 16);
            r0.x += acc[0]; r0.y += acc[1]; r0.z += acc[2]; r0.w += acc[3];
            r1.x += acc[4]; r1.y += acc[5]; r1.z += acc[6]; r1.w += acc[7];
            *(float4*)op        = r0;
            *(float4*)(op + 16) = r1;
        }
    }
}

// ---------------------------------------------------------------------------
// Slow fallback (tiny ws): fp32 dense + gather-aggregate on x directly.
// ---------------------------------------------------------------------------
__global__ __launch_bounds__(256) void count_fb_kernel(const int* __restrict__ dst,
                                                       const int* __restrict__ et,
                                                       int* __restrict__ cnt, int E) {
    int e = blockIdx.x * 256 + threadIdx.x;
    if (e < E) atomicAdd(&cnt[dst[e] * N_REL + et[e]], 1);
}

template<bool RELU>
__global__ __launch_bounds__(256) void dense_old_kernel(const float* __restrict__ x,
                                                        const float* __restrict__ root,
                                                        const float* __restrict__ bias,
                                                        float* __restrict__ out) {
    const int wv = threadIdx.x >> 6;
    const int l  = threadIdx.x & 63;
    const int wt = blockIdx.x * 4 + wv;
    if (wt >= NWT) return;
    const int nbase = wt * 16;
    const int lm = l & 15;
    const int kg = l >> 4;
    const int node = nbase + lm;

    s8v bfr[4];
#pragma unroll
    for (int kc = 0; kc < 4; ++kc) {
        const float* xp = &x[(size_t)node * DIM + kc * BS + kg * 8];
#pragma unroll
        for (int i = 0; i < 8; ++i) {
            float v = xp[i];
            if (RELU) v = fmaxf(v, 0.f);
            bfr[kc][i] = (short)f2bfbits(v);
        }
    }
#pragma unroll 2
    for (int mt = 0; mt < 8; ++mt) {
        const int col0 = mt * 16 + kg * 4;
        f4v acc = *(const f4v*)&bias[col0];
#pragma unroll
        for (int kc = 0; kc < 4; ++kc) {
            const float* rp = &root[(size_t)(kc * BS + kg * 8) * DIM + mt * 16 + lm];
            s8v afrag;
#pragma unroll
            for (int i = 0; i < 8; ++i)
                afrag[i] = (short)f2bfbits(rp[i * DIM]);
            acc = __builtin_amdgcn_mfma_f32_16x16x32_bf16(afrag, bfr[kc], acc, 0, 0, 0);
        }
        *(f4v*)&out[(size_t)node * DIM + col0] = acc;
    }
}

template<bool RELU>
__global__ __launch_bounds__(256) void agg_fallback_kernel(const int* __restrict__ srcs,
                                                           const int* __restrict__ off,
                                                           const int* __restrict__ cnt,
                                                           const float* __restrict__ x,
                                                           const float* __restrict__ W,
                                                           float* __restrict__ out) {
    __shared__ float Wsh[N_REL * BS * BS];
    const int bblk = blockIdx.y;
    for (int idx = threadIdx.x * 4; idx < N_REL * BS * BS; idx += 1024) {
        int r = idx >> 10, rest = idx & 1023;
        *(float4*)&Wsh[idx] = *(const float4*)&W[(r * NBLK + bblk) * 1024 + rest];
    }
    __syncthreads();
    const int hw = threadIdx.x >> 5;
    const int o  = threadIdx.x & 31;
    const int v  = blockIdx.x * 8 + hw;
    int endv = 0, cv = 0;
    if (o < N_REL) { endv = off[v * N_REL + o]; cv = cnt[v * N_REL + o]; }
    float acc = out[v * DIM + bblk * BS + o];
    for (int r = 0; r < N_REL; ++r) {
        const int c = __shfl(cv, r, 32);
        if (c == 0) continue;
        const int end = __shfl(endv, r, 32);
        float xs = 0.f;
        for (int k = end - c; k < end; ++k) {
            const int s = srcs[k];
            float xv = x[s * DIM + bblk * BS + o];
            if (RELU) xv = fmaxf(xv, 0.f);
            xs += xv;
        }
        xs *= (1.0f / (float)c);
        const float* wr = &Wsh[r * (BS * BS)];
#pragma unroll
        for (int i = 0; i < BS; i += 2) {
            float xi0 = __shfl(xs, i, 32);
            float xi1 = __shfl(xs, i + 1, 32);
            acc = fmaf(xi0, wr[i * BS + o], acc);
            acc = fmaf(xi1, wr[(i + 1) * BS + o], acc);
        }
    }
    out[v * DIM + bblk * BS + o] = acc;
}

// ---------------------------------------------------------------------------
extern "C" void kernel_launch(void* const* d_in, const int* in_sizes, int n_in,
                              void* d_out, int out_size, void* d_ws, size_t ws_size,
                              hipStream_t stream) {
    const int*   edge_index = (const int*)d_in[0];
    const int*   src   = edge_index;
    const int*   dstv  = edge_index + N_EDGES;
    const int*   et    = (const int*)d_in[1];
    const float* x0    = (const float*)d_in[2];
    const float* W1    = (const float*)d_in[3];
    const float* root1 = (const float*)d_in[4];
    const float* bias1 = (const float*)d_in[5];
    const float* W2    = (const float*)d_in[6];
    const float* root2 = (const float*)d_in[7];
    const float* bias2 = (const float*)d_in[8];
    float* out = (float*)d_out;

    // ---- fast-path workspace layout (138.2 MB total) ----
    char* ws = (char*)d_ws;
    ushort* h    = (ushort*)ws;                             // 12,800,000 (bf16)
    int*    cnt  = (int*)   (ws + 12800000);                //  3,200,000
    int*    used = (int*)   (ws + 16000000);                //  3,200,000 (adj to cnt)
    int*    off  = (int*)   (ws + 19200000);                //  3,200,000
    int*    cmap = (int*)   (ws + 22400000);                //  3,200,000
    int2*   evec = (int2*)  (ws + 25600000);                //  6,400,000
    int2*   bsum = (int2*)  (ws + 32000000);                //      8,192
    ushort* WB1  = (ushort*)(ws + 32008192);                //    262,144
    ushort* WB2  = (ushort*)(ws + 32270336);                //    262,144
    ushort* RB1  = (ushort*)(ws + 32532480);                //     32,768
    ushort* RB2  = (ushort*)(ws + 32565248);                //     32,768
    float*  scl  = (float*) (ws + 32598016);                //  3,200,000
    char*   tab  =          (ws + 35798016);                // 102,400,000
    const size_t FAST_NEED = 138198016ull;

    const int egrid = (N_EDGES + 255) / 256;     // 3125

    if (ws_size >= FAST_NEED) {
        prep_kernel<<<1152, 256, 0, stream>>>(W1, W2, root1, root2, WB1, WB2,
                                              RB1, RB2, (uint4*)cnt);
        count_kernel<<<egrid, 256, 0, stream>>>(src, dstv, et, cnt, used, N_EDGES);
        scan1j_kernel<<<N_SCAN_BLKS, 256, 0, stream>>>(cnt, used, off, cmap, bsum, NSEG);
        scan2j_kernel<<<1, 1024, 0, stream>>>(bsum, N_SCAN_BLKS);

        const int ngrid = N_NODES / 8;           // 6250

        // ---- layer 1: fused transform+dense + trailing SCATTER blocks ----
        fused_kernel<false, true, false, true><<<2 * NWTB + SCATB, 256, 0, stream>>>(
            x0, WB1, RB1, bias1, cmap, bsum, tab, scl, h,
            src, dstv, et, off, cnt, evec);
        agg8_kernel<true><<<ngrid, 256, 0, stream>>>(evec, off, bsum, tab, scl, h);

        // ---- layer 2: fused transform+dense ----
        fused_kernel<true, false, true, false><<<2 * NWTB, 256, 0, stream>>>(
            h, WB2, RB2, bias2, cmap, bsum, tab, scl, out,
            src, dstv, et, off, cnt, evec);
        agg8_kernel<false><<<ngrid, 256, 0, stream>>>(evec, off, bsum, tab, scl, out);
    } else {
        // ---- slow fallback (ws >= 35.3 MB): fp32 h + direct gather-agg ----
        float* hf    = (float*)d_ws;
        int*   cntf  = (int*)((char*)d_ws + 25600000);
        int*   offf  = (int*)((char*)d_ws + 28800000);
        int*   srcsf = (int*)((char*)d_ws + 32000000);
        int*   bsumf = (int*)((char*)d_ws + 35200000);

        hipMemsetAsync(cntf, 0, (size_t)NSEG * sizeof(int), stream);
        count_fb_kernel<<<egrid, 256, 0, stream>>>(dstv, et, cntf, N_EDGES);
        scan1_kernel<<<N_SCAN_BLKS, 256, 0, stream>>>(cntf, offf, bsumf, NSEG);
        scan2_kernel<<<1, 1024, 0, stream>>>(bsumf, N_SCAN_BLKS);
        scan3_kernel<<<(NSEG + 255) / 256, 256, 0, stream>>>(offf, bsumf, NSEG);
        scatter_old_kernel<<<egrid, 256, 0, stream>>>(src, dstv, et, offf, srcsf, N_EDGES);

        dim3 fgrid2(N_NODES / 8, NBLK);
        dense_old_kernel<false><<<NWTB, 256, 0, stream>>>(x0, root1, bias1, hf);
        agg_fallback_kernel<false><<<fgrid2, 256, 0, stream>>>(srcsf, offf, cntf, x0, W1, hf);
        dense_old_kernel<true><<<NWTB, 256, 0, stream>>>(hf, root2, bias2, out);
        agg_fallback_kernel<true><<<fgrid2, 256, 0, stream>>>(srcsf, offf, cntf, hf, W2, out);
    }
}